// Round 6
// baseline (426.870 us; speedup 1.0000x reference)
//
#include <hip/hip_runtime.h>
#include <cfloat>
#include <cmath>

typedef short short8 __attribute__((ext_vector_type(8)));
typedef unsigned short ushort8 __attribute__((ext_vector_type(8)));
typedef float f32x16 __attribute__((ext_vector_type(16)));
typedef double double4v __attribute__((ext_vector_type(4)));

#define K_CODES 8192
#define DIM 256
#define NQ_TOTAL 32768
#define CSPLIT 8
#define NSTAGE 17          /* 16 data stages + 1 norm stage */
#define NSTEP 68           /* 4 double-tiles (256 codes) x 17 stages */
#define PDEPTH 4           /* A-pipeline depth (register slots) */
#define TOPS 4             /* per-slice top-N stored */

/* ws layout (byte offsets) — identical to R4 */
#define WS_COUNTS 0          /* int[8192]            32 KB (zeroed) */
#define WS_LOSSQ  32768      /* float[32768]        128 KB */
#define WS_NORMS  163840     /* float[8192]          32 KB */
#define WS_PKD    196608     /* double[8*32768*4]     8 MB */
#define WS_ET     8585216    /* float[8192*256]       8 MB */
#define WS_AHI    16973824   /* ushort[64*17*4*64*8]  4.25 MB */
#define WS_BHI    21430272   /* ushort[512*17*2*64*8] 17 MB */

__device__ inline unsigned short f32_to_bf16_rne(float x) {
    unsigned u = __builtin_bit_cast(unsigned, x);
    unsigned r = u + 0x7FFFu + ((u >> 16) & 1u);
    return (unsigned short)(r >> 16);
}
__device__ inline float bf16_to_f32(unsigned short hh) {
    unsigned u = ((unsigned)hh) << 16;
    return __builtin_bit_cast(float, u);
}

// order-preserving f32 -> u32 flip (exact, lossless): monotone under u32 compare
__device__ inline unsigned flip32(float f) {
    unsigned u = __builtin_bit_cast(unsigned, f);
    return u ^ ((unsigned)((int)u >> 31) | 0x80000000u);
}

// f64 packed key (cold path only): value-exact f32 score, 13-bit code in low
// mantissa bits. Distinct f32 scores differ by >= 2^(e-23) as doubles; code
// perturbs by < 2^(e-39) -> score compare EXACT, code breaks exact ties only.
__device__ inline double mk_key(float v, int code) {
    unsigned long long b = __builtin_bit_cast(unsigned long long, (double)v)
                         | (unsigned long long)(unsigned)code;
    return __builtin_bit_cast(double, b);
}
// inverse of flip32 + repack as f64 key (cold: 8 uses per lane)
__device__ inline double key_from(unsigned k, unsigned c) {
    unsigned u = k ^ ((unsigned)((int)(~k) >> 31) | 0x80000000u);
    return mk_key(__builtin_bit_cast(float, u), (int)c);
}

// branchless sorted-descending top-4 insert on (u32 key, u32 code) pairs:
// per level v_cmp_gt_u32 + v_max_u32 + v_min_u32 + 2 v_cndmask — all full-rate
// (the f64 ladder's v_max_f64/min_f64 are ~1/4-rate; same exact semantics).
__device__ inline void ins4p(unsigned k, unsigned c, unsigned* tv, unsigned* tc) {
#pragma unroll
    for (int j = 0; j < TOPS; ++j) {
        bool g = k > tv[j];
        unsigned hv = g ? k : tv[j], lv = g ? tv[j] : k;
        unsigned hc = g ? c : tc[j], lc = g ? tc[j] : c;
        tv[j] = hv; tc[j] = hc; k = lv; c = lc;
    }
}

// branchless sorted-descending top-4 insert on f64 keys (cold merge path)
__device__ inline void ins4d(double k, double* tk) {
#pragma unroll
    for (int j = 0; j < TOPS; ++j) {
        double hi = fmax(k, tk[j]);
        double lo = fmin(k, tk[j]);
        tk[j] = hi; k = lo;
    }
}

// ---------------------------------------------------------------- fused E prep
__global__ __launch_bounds__(256) void prep_E(const float* __restrict__ E,
                                              unsigned short* __restrict__ Ahi,
                                              float* __restrict__ ET,
                                              float* __restrict__ norms) {
    __shared__ float part[8][32];
    const int tid = threadIdx.x;
    const int cl = tid & 31, g = tid >> 5;        // g in 0..7
    const int c0 = blockIdx.x * 32;               // 256 blocks
    const int c = c0 + cl;
    float ssum = 0.f;
#pragma unroll
    for (int i = 0; i < 4; ++i) {
        const int db = g + 8 * i;                 // db in 0..31 (8 dims each)
        float xs[8];
#pragma unroll
        for (int j = 0; j < 8; ++j) {
            xs[j] = E[(size_t)(db * 8 + j) * K_CODES + c];
            ssum += xs[j] * xs[j];
        }
        float4 f0 = {xs[0], xs[1], xs[2], xs[3]}, f1 = {xs[4], xs[5], xs[6], xs[7]};
        *(float4*)&ET[(size_t)c * DIM + db * 8]     = f0;
        *(float4*)&ET[(size_t)c * DIM + db * 8 + 4] = f1;
        ushort8 vh;
#pragma unroll
        for (int j = 0; j < 8; ++j) vh[j] = f32_to_bf16_rne(xs[j]);
        const int ct = c >> 7, mt = (c >> 5) & 3, lc = c & 31, s = db >> 1, hh = db & 1;
        const int lane2 = lc + 32 * hh;
        size_t chunk = ((((size_t)ct * NSTAGE + s) * 4 + mt) * 64 + lane2) * 8;
        *(ushort8*)&Ahi[chunk] = vh;
    }
    part[g][cl] = ssum;
    __syncthreads();
    if (tid < 64) {                               // A norm-stage chunk for this (ct, mt)
        const int ct = c0 >> 7, mt = (c0 >> 5) & 3;
        ushort8 v = {0, 0, 0, 0, 0, 0, 0, 0};
        if (tid < 32) {
            float nrm = 0.f;
#pragma unroll
            for (int gg = 0; gg < 8; ++gg) nrm += part[gg][tid];
            norms[c0 + tid] = nrm;
            unsigned short hi = f32_to_bf16_rne(nrm);
            unsigned short lo = f32_to_bf16_rne(nrm - bf16_to_f32(hi));
            v[0] = hi; v[1] = lo;
        }
        size_t chunk = ((((size_t)ct * NSTAGE + 16) * 4 + mt) * 64 + tid) * 8;
        *(ushort8*)&Ahi[chunk] = v;
    }
}

// ---------------------------------------------------------------- pack X -> frag-linear bf16
// blocks [0, 4096): X data stages; blocks [4096, 4352): B norm-stage constants.
#define XBLOCKS 4096
__global__ __launch_bounds__(256) void pack_XB(const float* __restrict__ X,
                                               unsigned short* __restrict__ Bhi) {
    const int bid = blockIdx.x;
    if (bid >= XBLOCKS) {                         // B norm-stage: -0.5 at k=0,1
        int id = (bid - XBLOCKS) * 256 + threadIdx.x;   // 65536 total
        int lane = id & 63, nt = (id >> 6) & 1, qt = id >> 7;
        ushort8 v = {0, 0, 0, 0, 0, 0, 0, 0};
        if (lane < 32) { v[0] = 0xBF00; v[1] = 0xBF00; }   // bf16(-0.5)
        size_t chunk = ((((size_t)qt * NSTAGE + 16) * 2 + nt) * 64 + lane) * 8;
        *(ushort8*)&Bhi[chunk] = v;
        return;
    }
    int id = bid * 256 + threadIdx.x;             // 1048576 total
    int q = id >> 5, db = id & 31;
    const float* src = X + (size_t)q * DIM + db * 8;
    float4 a = *(const float4*)src, b = *(const float4*)(src + 4);
    float xs[8] = {a.x, a.y, a.z, a.w, b.x, b.y, b.z, b.w};
    ushort8 vh;
#pragma unroll
    for (int i = 0; i < 8; ++i) vh[i] = f32_to_bf16_rne(xs[i]);
    int qt = q >> 6, nt = (q >> 5) & 1, lq = q & 31, s = db >> 1, hh = db & 1;
    int lane = lq + 32 * hh;
    size_t chunk = ((((size_t)qt * NSTAGE + s) * 2 + nt) * 64 + lane) * 8;
    *(ushort8*)&Bhi[chunk] = vh;
}

// ---------------------------------------------------------------- MFMA argmax — barrier-free K-loop
// R6 = R4 structure (B 17 stages in LDS — R5's occupancy theory falsified,
// R4 measured faster) with the hot scan moved from 1/4-rate f64 max/min to
// full-rate u32 (key,code) pair ladder. Cold merge path reconstructs the
// identical f64 packed keys -> downstream bit-compatible with R4.
__global__ __launch_bounds__(256, 3) void argmax_mfma(
        const unsigned short* __restrict__ Ahi, const unsigned short* __restrict__ Bhi,
        double* __restrict__ pkd) {
    __shared__ __align__(16) char smem[34816];                 // B: 17*2*512 shorts
    unsigned short* Bs = (unsigned short*)smem;
    double (*pks)[64][TOPS] = (double (*)[64][TOPS])smem;      // merge aliases B (16 KB)

    const int tid = threadIdx.x;
    const int lane = tid & 63, w = tid >> 6;
    const int th = w >> 1, wm = w & 1;             // tile-half, chunk-pair
    const int h = lane >> 5;
    const int cs = blockIdx.x, qt = blockIdx.y;

    // ---- stage B once: 34 x 1KB chunks (wave-strided)
#pragma unroll
    for (int i = 0; i < 9; ++i) {
        const int g = w + 4 * i;
        if (g < 34) {
            const unsigned short* src = Bhi + (((size_t)qt * 34 + g) * 64 + lane) * 8;
            __builtin_amdgcn_global_load_lds(
                (const __attribute__((address_space(1))) unsigned int*)src,
                (__attribute__((address_space(3))) unsigned int*)(Bs + g * 512), 16, 0, 0);
        }
    }

    // A stream for this wave: step t -> tile (cs*8 + (t/17)*2 + th), stage t%17, chunks wm*2,+1
    const unsigned short* Ab = Ahi + (((size_t)wm * 2) * 64 + lane) * 8;
#define A_OFF(t) ((((size_t)(cs * 8 + ((t) / NSTAGE) * 2 + th) * NSTAGE + ((t) % NSTAGE)) * 4) * 512)

    // prime the A register pipeline (in flight during B staging)
    short8 ap[PDEPTH][2];
#pragma unroll
    for (int p = 0; p < PDEPTH; ++p) {
        ap[p][0] = *(const short8*)(Ab + A_OFF(p));
        ap[p][1] = *(const short8*)(Ab + A_OFF(p) + 512);
    }
    __syncthreads();                               // B visible (drains prime loads too; one-time)

    unsigned tkv[2][TOPS], tkc[2][TOPS];
#pragma unroll
    for (int n2 = 0; n2 < 2; ++n2)
#pragma unroll
        for (int j = 0; j < TOPS; ++j) { tkv[n2][j] = 0u; tkc[n2][j] = 0u; }
        // key 0 = flip of a negative NaN — below every finite-score key

    f32x16 zc;
#pragma unroll
    for (int r = 0; r < 16; ++r) zc[r] = 0.f;
    f32x16 acc[2][2];

#pragma unroll
    for (int t = 0; t < NSTEP; ++t) {
        const int s = t % NSTAGE, slot = t % PDEPTH;
        short8 a0 = ap[slot][0], a1 = ap[slot][1];
        if (t + PDEPTH < NSTEP) {                  // refill slot for step t+PDEPTH
            ap[slot][0] = *(const short8*)(Ab + A_OFF(t + PDEPTH));
            ap[slot][1] = *(const short8*)(Ab + A_OFF(t + PDEPTH) + 512);
        }
        short8 b0 = *(const short8*)&Bs[(s * 2 + 0) * 512 + lane * 8];
        short8 b1 = *(const short8*)&Bs[(s * 2 + 1) * 512 + lane * 8];
        __builtin_amdgcn_s_setprio(1);
        if (s == 0) {                              // zero-C MFMA: no explicit acc clears
            acc[0][0] = __builtin_amdgcn_mfma_f32_32x32x16_bf16(a0, b0, zc, 0, 0, 0);
            acc[0][1] = __builtin_amdgcn_mfma_f32_32x32x16_bf16(a0, b1, zc, 0, 0, 0);
            acc[1][0] = __builtin_amdgcn_mfma_f32_32x32x16_bf16(a1, b0, zc, 0, 0, 0);
            acc[1][1] = __builtin_amdgcn_mfma_f32_32x32x16_bf16(a1, b1, zc, 0, 0, 0);
        } else {
            acc[0][0] = __builtin_amdgcn_mfma_f32_32x32x16_bf16(a0, b0, acc[0][0], 0, 0, 0);
            acc[0][1] = __builtin_amdgcn_mfma_f32_32x32x16_bf16(a0, b1, acc[0][1], 0, 0, 0);
            acc[1][0] = __builtin_amdgcn_mfma_f32_32x32x16_bf16(a1, b0, acc[1][0], 0, 0, 0);
            acc[1][1] = __builtin_amdgcn_mfma_f32_32x32x16_bf16(a1, b1, acc[1][1], 0, 0, 0);
        }
        __builtin_amdgcn_s_setprio(0);

        if (s == NSTAGE - 1) {                     // tile done: acc = score/2, norms folded
            const int cb2 = (cs * 8 + (t / NSTAGE) * 2 + th) * 128 + wm * 64 + 4 * h;
#pragma unroll
            for (int mt = 0; mt < 2; ++mt) {
#pragma unroll
                for (int r = 0; r < 16; ++r) {
                    const unsigned code = (unsigned)(cb2 + mt * 32 + (r & 3) + 8 * (r >> 2));
#pragma unroll
                    for (int n2 = 0; n2 < 2; ++n2)
                        ins4p(flip32(acc[mt][n2][r]), code, tkv[n2], tkc[n2]);
                }
            }
        }
    }
#undef A_OFF

    __syncthreads();                               // all B reads done before merge aliases B
    const int slot8 = w * 2 + h;                   // 8 cells per query column
#pragma unroll
    for (int n2 = 0; n2 < 2; ++n2) {
        const int ql = n2 * 32 + (lane & 31);
#pragma unroll
        for (int j = 0; j < TOPS; ++j)
            pks[slot8][ql][j] = key_from(tkv[n2][j], tkc[n2][j]);
    }
    __syncthreads();
    if (tid < 64) {
        double mk[TOPS];
#pragma unroll
        for (int j = 0; j < TOPS; ++j) mk[j] = -INFINITY;
#pragma unroll
        for (int sl = 0; sl < 8; ++sl)
#pragma unroll
            for (int j = 0; j < TOPS; ++j) ins4d(pks[sl][tid][j], mk);
        double4v o;
#pragma unroll
        for (int j = 0; j < TOPS; ++j) o[j] = mk[j];
        *(double4v*)&pkd[((size_t)cs * NQ_TOTAL + qt * 64 + tid) * TOPS] = o;
    }
}

// ---------------------------------------------------------------- candidate merge + exact rescore
__global__ __launch_bounds__(256) void finalize_q(
        const float* __restrict__ X, const float* __restrict__ ET,
        const float* __restrict__ norms, const double* __restrict__ pkd,
        float* __restrict__ outq, float* __restrict__ out_idx_f,
        float* __restrict__ loss_q, int* __restrict__ counts) {
    const int lane = threadIdx.x & 63, w = threadIdx.x >> 6;
    const int q = blockIdx.x * 4 + w;
    float4 x4 = *(const float4*)&X[(size_t)q * DIM + lane * 4];

    double wk = -INFINITY;
    if (lane < 32)
        wk = pkd[(((size_t)(lane >> 2) * NQ_TOTAL + q) * TOPS) + (lane & 3)];

    int kc[8];
#pragma unroll
    for (int t = 0; t < 8; ++t) {
        double m = wk;
#pragma unroll
        for (int o = 1; o < 64; o <<= 1) m = fmax(m, __shfl_xor(m, o));
        kc[t] = (int)(__builtin_bit_cast(unsigned long long, m) & 8191ull);
        if (wk == m) wk = -INFINITY;               // remove winner (keys unique)
    }

    float sb = -FLT_MAX; int kb = 0; float4 eb = x4;
#pragma unroll
    for (int t = 0; t < 8; ++t) {
        int k = kc[t];
        float4 e4 = *(const float4*)&ET[(size_t)k * DIM + lane * 4];
        float pr = x4.x * e4.x + x4.y * e4.y + x4.z * e4.z + x4.w * e4.w;
#pragma unroll
        for (int o = 1; o < 64; o <<= 1) pr += __shfl_xor(pr, o);
        float s = 2.f * pr - norms[k];
        bool better = (s > sb) || (s == sb && k < kb);
        if (better) { sb = s; kb = k; eb = e4; }
    }
    float4 d4 = {eb.x - x4.x, eb.y - x4.y, eb.z - x4.z, eb.w - x4.w};
    float4 o4 = {x4.x + d4.x, x4.y + d4.y, x4.z + d4.z, x4.w + d4.w};
    *(float4*)&outq[(size_t)q * DIM + lane * 4] = o4;
    float l = d4.x * d4.x + d4.y * d4.y + d4.z * d4.z + d4.w * d4.w;
#pragma unroll
    for (int o = 1; o < 64; o <<= 1) l += __shfl_xor(l, o);
    if (lane == 0) {
        out_idx_f[q] = (float)kb;
        loss_q[q] = l;
        atomicAdd(&counts[kb], 1);
    }
}

// ---------------------------------------------------------------- scalars
__global__ __launch_bounds__(256) void final_scalars(
        const int* __restrict__ counts, const float* __restrict__ loss_q,
        float* __restrict__ out_sc) {
    int t = threadIdx.x;
    float ls = 0.f;
    for (int i = t; i < NQ_TOTAL; i += 256) ls += loss_q[i];
    float ent = 0.f;
    for (int k = t; k < K_CODES; k += 256) {
        float p = (float)counts[k] / (float)NQ_TOTAL;
        ent -= p * logf(p + 1e-10f);
    }
#pragma unroll
    for (int o = 1; o < 64; o <<= 1) { ls += __shfl_xor(ls, o); ent += __shfl_xor(ent, o); }
    __shared__ float rl[4], re[4];
    if ((t & 63) == 0) { rl[t >> 6] = ls; re[t >> 6] = ent; }
    __syncthreads();
    if (t == 0) {
        float L = rl[0] + rl[1] + rl[2] + rl[3];
        float Ee = re[0] + re[1] + re[2] + re[3];
        float mse = L / (float)((size_t)NQ_TOTAL * DIM);
        out_sc[0] = 1.1f * mse;                         // e_latent + 0.1*q_latent
        out_sc[1] = -0.1f * (Ee / logf((float)K_CODES));
    }
}

extern "C" void kernel_launch(void* const* d_in, const int* in_sizes, int n_in,
                              void* d_out, int out_size, void* d_ws, size_t ws_size,
                              hipStream_t stream) {
    const float* X = (const float*)d_in[0];   // [32768, 256] fp32
    const float* E = (const float*)d_in[1];   // [256, 8192]  fp32

    float* out       = (float*)d_out;
    float* outq      = out;                           // 8388608
    float* out_idx_f = out + (size_t)NQ_TOTAL * DIM;  // 32768 (indices as f32)
    float* out_sc    = out_idx_f + NQ_TOTAL;          // 2 scalars

    char* ws = (char*)d_ws;
    int*            counts = (int*)(ws + WS_COUNTS);
    float*          loss_q = (float*)(ws + WS_LOSSQ);
    float*          norms  = (float*)(ws + WS_NORMS);
    double*         pkd    = (double*)(ws + WS_PKD);
    float*          ET     = (float*)(ws + WS_ET);
    unsigned short* Ahi    = (unsigned short*)(ws + WS_AHI);
    unsigned short* Bhi    = (unsigned short*)(ws + WS_BHI);

    hipMemsetAsync(counts, 0, K_CODES * sizeof(int), stream);
    prep_E<<<K_CODES / 32, 256, 0, stream>>>(E, Ahi, ET, norms);
    pack_XB<<<XBLOCKS + 256, 256, 0, stream>>>(X, Bhi);
    argmax_mfma<<<dim3(CSPLIT, NQ_TOTAL / 64), 256, 0, stream>>>(Ahi, Bhi, pkd);
    finalize_q<<<NQ_TOTAL / 4, 256, 0, stream>>>(X, ET, norms, pkd, outq, out_idx_f, loss_q, counts);
    final_scalars<<<1, 256, 0, stream>>>(counts, loss_q, out_sc);
}

// Round 7
// 377.187 us; speedup vs baseline: 1.1317x; 1.1317x over previous
//
#include <hip/hip_runtime.h>
#include <cfloat>
#include <cmath>

typedef short short8 __attribute__((ext_vector_type(8)));
typedef unsigned short ushort8 __attribute__((ext_vector_type(8)));
typedef float f32x16 __attribute__((ext_vector_type(16)));
typedef double double4v __attribute__((ext_vector_type(4)));

#define K_CODES 8192
#define DIM 256
#define NQ_TOTAL 32768
#define CSPLIT 8
#define NSTAGE 17          /* 16 data stages + 1 norm stage */
#define NSTEP 68           /* 4 double-tiles (256 codes) x 17 stages */
#define PDEPTH 2           /* A-pipeline depth — 2 slots keeps arch VGPR <= 64 */
#define TOPS 4             /* per-slice top-N stored */

/* ws layout (byte offsets) — identical to R4 */
#define WS_COUNTS 0          /* int[8192]            32 KB (zeroed) */
#define WS_LOSSQ  32768      /* float[32768]        128 KB */
#define WS_NORMS  163840     /* float[8192]          32 KB */
#define WS_PKD    196608     /* double[8*32768*4]     8 MB */
#define WS_ET     8585216    /* float[8192*256]       8 MB */
#define WS_AHI    16973824   /* ushort[64*17*4*64*8]  4.25 MB */
#define WS_BHI    21430272   /* ushort[512*17*2*64*8] 17 MB */

__device__ inline unsigned short f32_to_bf16_rne(float x) {
    unsigned u = __builtin_bit_cast(unsigned, x);
    unsigned r = u + 0x7FFFu + ((u >> 16) & 1u);
    return (unsigned short)(r >> 16);
}
__device__ inline float bf16_to_f32(unsigned short hh) {
    unsigned u = ((unsigned)hh) << 16;
    return __builtin_bit_cast(float, u);
}

// f64 packed key: value-exact f32 score in high bits, 13-bit code in the
// (otherwise zero) low mantissa bits. Distinct f32 scores differ by >= 2^(e-23)
// as doubles; code perturbs by < 2^(e-39) -> score compare is EXACT; code bits
// only break exact-score ties. NaN impossible (finite acc).
// R6 lesson: ONE full-rate 64-bit max/min moves value+code together — cheaper
// than any (u32,u32) pair ladder (5 dependent ops/level).
__device__ inline double mk_key(float v, int code) {
    unsigned long long b = __builtin_bit_cast(unsigned long long, (double)v)
                         | (unsigned long long)(unsigned)code;
    return __builtin_bit_cast(double, b);
}

// branchless sorted-descending top-4 insert (v_max_f64 / v_min_f64 ladder)
__device__ inline void ins4d(double k, double* tk) {
#pragma unroll
    for (int j = 0; j < TOPS; ++j) {
        double hi = fmax(k, tk[j]);
        double lo = fmin(k, tk[j]);
        tk[j] = hi; k = lo;
    }
}

// ---------------------------------------------------------------- fused E prep
__global__ __launch_bounds__(256) void prep_E(const float* __restrict__ E,
                                              unsigned short* __restrict__ Ahi,
                                              float* __restrict__ ET,
                                              float* __restrict__ norms) {
    __shared__ float part[8][32];
    const int tid = threadIdx.x;
    const int cl = tid & 31, g = tid >> 5;        // g in 0..7
    const int c0 = blockIdx.x * 32;               // 256 blocks
    const int c = c0 + cl;
    float ssum = 0.f;
#pragma unroll
    for (int i = 0; i < 4; ++i) {
        const int db = g + 8 * i;                 // db in 0..31 (8 dims each)
        float xs[8];
#pragma unroll
        for (int j = 0; j < 8; ++j) {
            xs[j] = E[(size_t)(db * 8 + j) * K_CODES + c];
            ssum += xs[j] * xs[j];
        }
        float4 f0 = {xs[0], xs[1], xs[2], xs[3]}, f1 = {xs[4], xs[5], xs[6], xs[7]};
        *(float4*)&ET[(size_t)c * DIM + db * 8]     = f0;
        *(float4*)&ET[(size_t)c * DIM + db * 8 + 4] = f1;
        ushort8 vh;
#pragma unroll
        for (int j = 0; j < 8; ++j) vh[j] = f32_to_bf16_rne(xs[j]);
        const int ct = c >> 7, mt = (c >> 5) & 3, lc = c & 31, s = db >> 1, hh = db & 1;
        const int lane2 = lc + 32 * hh;
        size_t chunk = ((((size_t)ct * NSTAGE + s) * 4 + mt) * 64 + lane2) * 8;
        *(ushort8*)&Ahi[chunk] = vh;
    }
    part[g][cl] = ssum;
    __syncthreads();
    if (tid < 64) {                               // A norm-stage chunk for this (ct, mt)
        const int ct = c0 >> 7, mt = (c0 >> 5) & 3;
        ushort8 v = {0, 0, 0, 0, 0, 0, 0, 0};
        if (tid < 32) {
            float nrm = 0.f;
#pragma unroll
            for (int gg = 0; gg < 8; ++gg) nrm += part[gg][tid];
            norms[c0 + tid] = nrm;
            unsigned short hi = f32_to_bf16_rne(nrm);
            unsigned short lo = f32_to_bf16_rne(nrm - bf16_to_f32(hi));
            v[0] = hi; v[1] = lo;
        }
        size_t chunk = ((((size_t)ct * NSTAGE + 16) * 4 + mt) * 64 + tid) * 8;
        *(ushort8*)&Ahi[chunk] = v;
    }
}

// ---------------------------------------------------------------- pack X -> frag-linear bf16
// blocks [0, 4096): X data stages; blocks [4096, 4352): B norm-stage constants.
#define XBLOCKS 4096
__global__ __launch_bounds__(256) void pack_XB(const float* __restrict__ X,
                                               unsigned short* __restrict__ Bhi) {
    const int bid = blockIdx.x;
    if (bid >= XBLOCKS) {                         // B norm-stage: -0.5 at k=0,1
        int id = (bid - XBLOCKS) * 256 + threadIdx.x;   // 65536 total
        int lane = id & 63, nt = (id >> 6) & 1, qt = id >> 7;
        ushort8 v = {0, 0, 0, 0, 0, 0, 0, 0};
        if (lane < 32) { v[0] = 0xBF00; v[1] = 0xBF00; }   // bf16(-0.5)
        size_t chunk = ((((size_t)qt * NSTAGE + 16) * 2 + nt) * 64 + lane) * 8;
        *(ushort8*)&Bhi[chunk] = v;
        return;
    }
    int id = bid * 256 + threadIdx.x;             // 1048576 total
    int q = id >> 5, db = id & 31;
    const float* src = X + (size_t)q * DIM + db * 8;
    float4 a = *(const float4*)src, b = *(const float4*)(src + 4);
    float xs[8] = {a.x, a.y, a.z, a.w, b.x, b.y, b.z, b.w};
    ushort8 vh;
#pragma unroll
    for (int i = 0; i < 8; ++i) vh[i] = f32_to_bf16_rne(xs[i]);
    int qt = q >> 6, nt = (q >> 5) & 1, lq = q & 31, s = db >> 1, hh = db & 1;
    int lane = lq + 32 * hh;
    size_t chunk = ((((size_t)qt * NSTAGE + s) * 2 + nt) * 64 + lane) * 8;
    *(ushort8*)&Bhi[chunk] = vh;
}

// ---------------------------------------------------------------- MFMA argmax — barrier-free K-loop
// R7 = R4's f64-key scan + R3's register budget. Occupancy was VGPR-limited:
// arch 72 + acc 64 = 136 -> 3 waves/SIMD (R4/R5/R6 all 31%); at arch 64 the
// total is 128 -> 4 waves/SIMD (R3 measured 38%). PDEPTH 4->2 frees the 16
// arch VGPRs; __launch_bounds__(256,4) pins the allocator to the 128 budget.
__global__ __launch_bounds__(256, 4) void argmax_mfma(
        const unsigned short* __restrict__ Ahi, const unsigned short* __restrict__ Bhi,
        double* __restrict__ pkd) {
    __shared__ __align__(16) char smem[34816];                 // B: 17*2*512 shorts
    unsigned short* Bs = (unsigned short*)smem;
    double (*pks)[64][TOPS] = (double (*)[64][TOPS])smem;      // merge aliases B (16 KB)

    const int tid = threadIdx.x;
    const int lane = tid & 63, w = tid >> 6;
    const int th = w >> 1, wm = w & 1;             // tile-half, chunk-pair
    const int h = lane >> 5;
    const int cs = blockIdx.x, qt = blockIdx.y;

    // ---- stage B once: 34 x 1KB chunks (wave-strided)
#pragma unroll
    for (int i = 0; i < 9; ++i) {
        const int g = w + 4 * i;
        if (g < 34) {
            const unsigned short* src = Bhi + (((size_t)qt * 34 + g) * 64 + lane) * 8;
            __builtin_amdgcn_global_load_lds(
                (const __attribute__((address_space(1))) unsigned int*)src,
                (__attribute__((address_space(3))) unsigned int*)(Bs + g * 512), 16, 0, 0);
        }
    }

    // A stream for this wave: step t -> tile (cs*8 + (t/17)*2 + th), stage t%17, chunks wm*2,+1
    const unsigned short* Ab = Ahi + (((size_t)wm * 2) * 64 + lane) * 8;
#define A_OFF(t) ((((size_t)(cs * 8 + ((t) / NSTAGE) * 2 + th) * NSTAGE + ((t) % NSTAGE)) * 4) * 512)

    // prime the A register pipeline (in flight during B staging)
    short8 ap[PDEPTH][2];
#pragma unroll
    for (int p = 0; p < PDEPTH; ++p) {
        ap[p][0] = *(const short8*)(Ab + A_OFF(p));
        ap[p][1] = *(const short8*)(Ab + A_OFF(p) + 512);
    }
    __syncthreads();                               // B visible (drains prime loads too; one-time)

    double tk[2][TOPS];
#pragma unroll
    for (int n2 = 0; n2 < 2; ++n2)
#pragma unroll
        for (int j = 0; j < TOPS; ++j) tk[n2][j] = -INFINITY;

    f32x16 zc;
#pragma unroll
    for (int r = 0; r < 16; ++r) zc[r] = 0.f;
    f32x16 acc[2][2];

#pragma unroll
    for (int t = 0; t < NSTEP; ++t) {
        const int s = t % NSTAGE, slot = t % PDEPTH;
        short8 a0 = ap[slot][0], a1 = ap[slot][1];
        if (t + PDEPTH < NSTEP) {                  // refill slot for step t+PDEPTH
            ap[slot][0] = *(const short8*)(Ab + A_OFF(t + PDEPTH));
            ap[slot][1] = *(const short8*)(Ab + A_OFF(t + PDEPTH) + 512);
        }
        short8 b0 = *(const short8*)&Bs[(s * 2 + 0) * 512 + lane * 8];
        short8 b1 = *(const short8*)&Bs[(s * 2 + 1) * 512 + lane * 8];
        __builtin_amdgcn_s_setprio(1);
        if (s == 0) {                              // zero-C MFMA: no explicit acc clears
            acc[0][0] = __builtin_amdgcn_mfma_f32_32x32x16_bf16(a0, b0, zc, 0, 0, 0);
            acc[0][1] = __builtin_amdgcn_mfma_f32_32x32x16_bf16(a0, b1, zc, 0, 0, 0);
            acc[1][0] = __builtin_amdgcn_mfma_f32_32x32x16_bf16(a1, b0, zc, 0, 0, 0);
            acc[1][1] = __builtin_amdgcn_mfma_f32_32x32x16_bf16(a1, b1, zc, 0, 0, 0);
        } else {
            acc[0][0] = __builtin_amdgcn_mfma_f32_32x32x16_bf16(a0, b0, acc[0][0], 0, 0, 0);
            acc[0][1] = __builtin_amdgcn_mfma_f32_32x32x16_bf16(a0, b1, acc[0][1], 0, 0, 0);
            acc[1][0] = __builtin_amdgcn_mfma_f32_32x32x16_bf16(a1, b0, acc[1][0], 0, 0, 0);
            acc[1][1] = __builtin_amdgcn_mfma_f32_32x32x16_bf16(a1, b1, acc[1][1], 0, 0, 0);
        }
        __builtin_amdgcn_s_setprio(0);

        if (s == NSTAGE - 1) {                     // tile done: acc = score/2, norms folded
            const int cb2 = (cs * 8 + (t / NSTAGE) * 2 + th) * 128 + wm * 64 + 4 * h;
#pragma unroll
            for (int mt = 0; mt < 2; ++mt) {
#pragma unroll
                for (int r = 0; r < 16; ++r) {
                    const int code = cb2 + mt * 32 + (r & 3) + 8 * (r >> 2);
#pragma unroll
                    for (int n2 = 0; n2 < 2; ++n2)
                        ins4d(mk_key(acc[mt][n2][r], code), tk[n2]);
                }
            }
        }
    }
#undef A_OFF

    __syncthreads();                               // all B reads done before merge aliases B
    const int slot8 = w * 2 + h;                   // 8 cells per query column
#pragma unroll
    for (int n2 = 0; n2 < 2; ++n2) {
        const int ql = n2 * 32 + (lane & 31);
#pragma unroll
        for (int j = 0; j < TOPS; ++j) pks[slot8][ql][j] = tk[n2][j];
    }
    __syncthreads();
    if (tid < 64) {
        double mk[TOPS];
#pragma unroll
        for (int j = 0; j < TOPS; ++j) mk[j] = -INFINITY;
#pragma unroll
        for (int sl = 0; sl < 8; ++sl)
#pragma unroll
            for (int j = 0; j < TOPS; ++j) ins4d(pks[sl][tid][j], mk);
        double4v o;
#pragma unroll
        for (int j = 0; j < TOPS; ++j) o[j] = mk[j];
        *(double4v*)&pkd[((size_t)cs * NQ_TOTAL + qt * 64 + tid) * TOPS] = o;
    }
}

// ---------------------------------------------------------------- candidate merge + exact rescore
__global__ __launch_bounds__(256) void finalize_q(
        const float* __restrict__ X, const float* __restrict__ ET,
        const float* __restrict__ norms, const double* __restrict__ pkd,
        float* __restrict__ outq, float* __restrict__ out_idx_f,
        float* __restrict__ loss_q, int* __restrict__ counts) {
    const int lane = threadIdx.x & 63, w = threadIdx.x >> 6;
    const int q = blockIdx.x * 4 + w;
    float4 x4 = *(const float4*)&X[(size_t)q * DIM + lane * 4];

    double wk = -INFINITY;
    if (lane < 32)
        wk = pkd[(((size_t)(lane >> 2) * NQ_TOTAL + q) * TOPS) + (lane & 3)];

    int kc[8];
#pragma unroll
    for (int t = 0; t < 8; ++t) {
        double m = wk;
#pragma unroll
        for (int o = 1; o < 64; o <<= 1) m = fmax(m, __shfl_xor(m, o));
        kc[t] = (int)(__builtin_bit_cast(unsigned long long, m) & 8191ull);
        if (wk == m) wk = -INFINITY;               // remove winner (keys unique)
    }

    float sb = -FLT_MAX; int kb = 0; float4 eb = x4;
#pragma unroll
    for (int t = 0; t < 8; ++t) {
        int k = kc[t];
        float4 e4 = *(const float4*)&ET[(size_t)k * DIM + lane * 4];
        float pr = x4.x * e4.x + x4.y * e4.y + x4.z * e4.z + x4.w * e4.w;
#pragma unroll
        for (int o = 1; o < 64; o <<= 1) pr += __shfl_xor(pr, o);
        float s = 2.f * pr - norms[k];
        bool better = (s > sb) || (s == sb && k < kb);
        if (better) { sb = s; kb = k; eb = e4; }
    }
    float4 d4 = {eb.x - x4.x, eb.y - x4.y, eb.z - x4.z, eb.w - x4.w};
    float4 o4 = {x4.x + d4.x, x4.y + d4.y, x4.z + d4.z, x4.w + d4.w};
    *(float4*)&outq[(size_t)q * DIM + lane * 4] = o4;
    float l = d4.x * d4.x + d4.y * d4.y + d4.z * d4.z + d4.w * d4.w;
#pragma unroll
    for (int o = 1; o < 64; o <<= 1) l += __shfl_xor(l, o);
    if (lane == 0) {
        out_idx_f[q] = (float)kb;
        loss_q[q] = l;
        atomicAdd(&counts[kb], 1);
    }
}

// ---------------------------------------------------------------- scalars
__global__ __launch_bounds__(256) void final_scalars(
        const int* __restrict__ counts, const float* __restrict__ loss_q,
        float* __restrict__ out_sc) {
    int t = threadIdx.x;
    float ls = 0.f;
    for (int i = t; i < NQ_TOTAL; i += 256) ls += loss_q[i];
    float ent = 0.f;
    for (int k = t; k < K_CODES; k += 256) {
        float p = (float)counts[k] / (float)NQ_TOTAL;
        ent -= p * logf(p + 1e-10f);
    }
#pragma unroll
    for (int o = 1; o < 64; o <<= 1) { ls += __shfl_xor(ls, o); ent += __shfl_xor(ent, o); }
    __shared__ float rl[4], re[4];
    if ((t & 63) == 0) { rl[t >> 6] = ls; re[t >> 6] = ent; }
    __syncthreads();
    if (t == 0) {
        float L = rl[0] + rl[1] + rl[2] + rl[3];
        float Ee = re[0] + re[1] + re[2] + re[3];
        float mse = L / (float)((size_t)NQ_TOTAL * DIM);
        out_sc[0] = 1.1f * mse;                         // e_latent + 0.1*q_latent
        out_sc[1] = -0.1f * (Ee / logf((float)K_CODES));
    }
}

extern "C" void kernel_launch(void* const* d_in, const int* in_sizes, int n_in,
                              void* d_out, int out_size, void* d_ws, size_t ws_size,
                              hipStream_t stream) {
    const float* X = (const float*)d_in[0];   // [32768, 256] fp32
    const float* E = (const float*)d_in[1];   // [256, 8192]  fp32

    float* out       = (float*)d_out;
    float* outq      = out;                           // 8388608
    float* out_idx_f = out + (size_t)NQ_TOTAL * DIM;  // 32768 (indices as f32)
    float* out_sc    = out_idx_f + NQ_TOTAL;          // 2 scalars

    char* ws = (char*)d_ws;
    int*            counts = (int*)(ws + WS_COUNTS);
    float*          loss_q = (float*)(ws + WS_LOSSQ);
    float*          norms  = (float*)(ws + WS_NORMS);
    double*         pkd    = (double*)(ws + WS_PKD);
    float*          ET     = (float*)(ws + WS_ET);
    unsigned short* Ahi    = (unsigned short*)(ws + WS_AHI);
    unsigned short* Bhi    = (unsigned short*)(ws + WS_BHI);

    hipMemsetAsync(counts, 0, K_CODES * sizeof(int), stream);
    prep_E<<<K_CODES / 32, 256, 0, stream>>>(E, Ahi, ET, norms);
    pack_XB<<<XBLOCKS + 256, 256, 0, stream>>>(X, Bhi);
    argmax_mfma<<<dim3(CSPLIT, NQ_TOTAL / 64), 256, 0, stream>>>(Ahi, Bhi, pkd);
    finalize_q<<<NQ_TOTAL / 4, 256, 0, stream>>>(X, ET, norms, pkd, outq, out_idx_f, loss_q, counts);
    final_scalars<<<1, 256, 0, stream>>>(counts, loss_q, out_sc);
}

// Round 8
// 376.791 us; speedup vs baseline: 1.1329x; 1.0011x over previous
//
#include <hip/hip_runtime.h>
#include <cfloat>
#include <cmath>

typedef short short8 __attribute__((ext_vector_type(8)));
typedef unsigned short ushort8 __attribute__((ext_vector_type(8)));
typedef float f32x16 __attribute__((ext_vector_type(16)));
typedef double double4v __attribute__((ext_vector_type(4)));

#define K_CODES 8192
#define DIM 256
#define NQ_TOTAL 32768
#define CSPLIT 8
#define NSTAGE 17          /* 16 data stages + 1 norm stage */
#define NSTEP 68           /* 4 double-tiles (256 codes) x 17 stages */
#define PDEPTH 4           /* A-pipeline depth (R4 config — regs are free, see R7) */
#define TOPS 4             /* per-slice top-N stored */

/* ws layout (byte offsets) — identical to R4 */
#define WS_COUNTS 0          /* int[8192]            32 KB (zeroed) */
#define WS_LOSSQ  32768      /* float[32768]        128 KB */
#define WS_NORMS  163840     /* float[8192]          32 KB */
#define WS_PKD    196608     /* double[8*32768*4]     8 MB */
#define WS_ET     8585216    /* float[8192*256]       8 MB */
#define WS_AHI    16973824   /* ushort[64*17*4*64*8]  4.25 MB */
#define WS_BHI    21430272   /* ushort[512*17*2*64*8] 17 MB */

__device__ inline unsigned short f32_to_bf16_rne(float x) {
    unsigned u = __builtin_bit_cast(unsigned, x);
    unsigned r = u + 0x7FFFu + ((u >> 16) & 1u);
    return (unsigned short)(r >> 16);
}
__device__ inline float bf16_to_f32(unsigned short hh) {
    unsigned u = ((unsigned)hh) << 16;
    return __builtin_bit_cast(float, u);
}

// f64 packed key: value-exact f32 score in high bits, 13-bit code in the
// (otherwise zero) low mantissa bits. Distinct f32 scores differ by >= 2^(e-23)
// as doubles; code perturbs by < 2^(e-39) -> score compare is EXACT; code bits
// only break exact-score ties. One 64-bit max/min moves value+code together
// (R6: cheaper than any (u32,u32) pair ladder).
__device__ inline double mk_key(float v, int code) {
    unsigned long long b = __builtin_bit_cast(unsigned long long, (double)v)
                         | (unsigned long long)(unsigned)code;
    return __builtin_bit_cast(double, b);
}

// compare-exchange (descending): a=max, b=min — v_max_f64 + v_min_f64
__device__ inline void ced(double& a, double& b) {
    double hi = fmax(a, b), lo = fmin(a, b);
    a = hi; b = lo;
}
// full descending sort of 4 keys (5-CE network)
__device__ inline void sort4(double* q) {
    ced(q[0], q[1]); ced(q[2], q[3]); ced(q[0], q[2]); ced(q[1], q[3]); ced(q[1], q[2]);
}
// EXACT top-4 of (sorted-desc q[4], sorted-desc tk[4]) -> tk sorted-desc.
// Odd-even merge identity: top4 set = { max(q[i], tk[3-i]) }, then the result
// is bitonic -> 4-CE bitonic cleanup sorts it. 12 ops vs 32 for 4 ladder inserts.
__device__ inline void merge4(const double* q, double* tk) {
    double t0 = fmax(q[0], tk[3]);
    double t1 = fmax(q[1], tk[2]);
    double t2 = fmax(q[2], tk[1]);
    double t3 = fmax(q[3], tk[0]);
    ced(t0, t2); ced(t1, t3); ced(t0, t1); ced(t2, t3);
    tk[0] = t0; tk[1] = t1; tk[2] = t2; tk[3] = t3;
}

// ---------------------------------------------------------------- fused E prep
__global__ __launch_bounds__(256) void prep_E(const float* __restrict__ E,
                                              unsigned short* __restrict__ Ahi,
                                              float* __restrict__ ET,
                                              float* __restrict__ norms) {
    __shared__ float part[8][32];
    const int tid = threadIdx.x;
    const int cl = tid & 31, g = tid >> 5;        // g in 0..7
    const int c0 = blockIdx.x * 32;               // 256 blocks
    const int c = c0 + cl;
    float ssum = 0.f;
#pragma unroll
    for (int i = 0; i < 4; ++i) {
        const int db = g + 8 * i;                 // db in 0..31 (8 dims each)
        float xs[8];
#pragma unroll
        for (int j = 0; j < 8; ++j) {
            xs[j] = E[(size_t)(db * 8 + j) * K_CODES + c];
            ssum += xs[j] * xs[j];
        }
        float4 f0 = {xs[0], xs[1], xs[2], xs[3]}, f1 = {xs[4], xs[5], xs[6], xs[7]};
        *(float4*)&ET[(size_t)c * DIM + db * 8]     = f0;
        *(float4*)&ET[(size_t)c * DIM + db * 8 + 4] = f1;
        ushort8 vh;
#pragma unroll
        for (int j = 0; j < 8; ++j) vh[j] = f32_to_bf16_rne(xs[j]);
        const int ct = c >> 7, mt = (c >> 5) & 3, lc = c & 31, s = db >> 1, hh = db & 1;
        const int lane2 = lc + 32 * hh;
        size_t chunk = ((((size_t)ct * NSTAGE + s) * 4 + mt) * 64 + lane2) * 8;
        *(ushort8*)&Ahi[chunk] = vh;
    }
    part[g][cl] = ssum;
    __syncthreads();
    if (tid < 64) {                               // A norm-stage chunk for this (ct, mt)
        const int ct = c0 >> 7, mt = (c0 >> 5) & 3;
        ushort8 v = {0, 0, 0, 0, 0, 0, 0, 0};
        if (tid < 32) {
            float nrm = 0.f;
#pragma unroll
            for (int gg = 0; gg < 8; ++gg) nrm += part[gg][tid];
            norms[c0 + tid] = nrm;
            unsigned short hi = f32_to_bf16_rne(nrm);
            unsigned short lo = f32_to_bf16_rne(nrm - bf16_to_f32(hi));
            v[0] = hi; v[1] = lo;
        }
        size_t chunk = ((((size_t)ct * NSTAGE + 16) * 4 + mt) * 64 + tid) * 8;
        *(ushort8*)&Ahi[chunk] = v;
    }
}

// ---------------------------------------------------------------- pack X -> frag-linear bf16
// blocks [0, 4096): X data stages; blocks [4096, 4352): B norm-stage constants.
#define XBLOCKS 4096
__global__ __launch_bounds__(256) void pack_XB(const float* __restrict__ X,
                                               unsigned short* __restrict__ Bhi) {
    const int bid = blockIdx.x;
    if (bid >= XBLOCKS) {                         // B norm-stage: -0.5 at k=0,1
        int id = (bid - XBLOCKS) * 256 + threadIdx.x;   // 65536 total
        int lane = id & 63, nt = (id >> 6) & 1, qt = id >> 7;
        ushort8 v = {0, 0, 0, 0, 0, 0, 0, 0};
        if (lane < 32) { v[0] = 0xBF00; v[1] = 0xBF00; }   // bf16(-0.5)
        size_t chunk = ((((size_t)qt * NSTAGE + 16) * 2 + nt) * 64 + lane) * 8;
        *(ushort8*)&Bhi[chunk] = v;
        return;
    }
    int id = bid * 256 + threadIdx.x;             // 1048576 total
    int q = id >> 5, db = id & 31;
    const float* src = X + (size_t)q * DIM + db * 8;
    float4 a = *(const float4*)src, b = *(const float4*)(src + 4);
    float xs[8] = {a.x, a.y, a.z, a.w, b.x, b.y, b.z, b.w};
    ushort8 vh;
#pragma unroll
    for (int i = 0; i < 8; ++i) vh[i] = f32_to_bf16_rne(xs[i]);
    int qt = q >> 6, nt = (q >> 5) & 1, lq = q & 31, s = db >> 1, hh = db & 1;
    int lane = lq + 32 * hh;
    size_t chunk = ((((size_t)qt * NSTAGE + s) * 2 + nt) * 64 + lane) * 8;
    *(ushort8*)&Bhi[chunk] = vh;
}

// ---------------------------------------------------------------- MFMA argmax — barrier-free K-loop
// R8 = R4 config (PDEPTH=4, (256,3) — R7 proved occupancy is NOT the limiter;
// kernel is VALU-issue-bound) + quad sort4/merge4 scan: exact top-4, 5.5 ops/value
// vs the 8-op/value insertion ladder, and a 4x shorter serial tk chain.
__global__ __launch_bounds__(256, 3) void argmax_mfma(
        const unsigned short* __restrict__ Ahi, const unsigned short* __restrict__ Bhi,
        double* __restrict__ pkd) {
    __shared__ __align__(16) char smem[34816];                 // B: 17*2*512 shorts
    unsigned short* Bs = (unsigned short*)smem;
    double (*pks)[64][TOPS] = (double (*)[64][TOPS])smem;      // merge aliases B (16 KB)

    const int tid = threadIdx.x;
    const int lane = tid & 63, w = tid >> 6;
    const int th = w >> 1, wm = w & 1;             // tile-half, chunk-pair
    const int h = lane >> 5;
    const int cs = blockIdx.x, qt = blockIdx.y;

    // ---- stage B once: 34 x 1KB chunks (wave-strided)
#pragma unroll
    for (int i = 0; i < 9; ++i) {
        const int g = w + 4 * i;
        if (g < 34) {
            const unsigned short* src = Bhi + (((size_t)qt * 34 + g) * 64 + lane) * 8;
            __builtin_amdgcn_global_load_lds(
                (const __attribute__((address_space(1))) unsigned int*)src,
                (__attribute__((address_space(3))) unsigned int*)(Bs + g * 512), 16, 0, 0);
        }
    }

    // A stream for this wave: step t -> tile (cs*8 + (t/17)*2 + th), stage t%17, chunks wm*2,+1
    const unsigned short* Ab = Ahi + (((size_t)wm * 2) * 64 + lane) * 8;
#define A_OFF(t) ((((size_t)(cs * 8 + ((t) / NSTAGE) * 2 + th) * NSTAGE + ((t) % NSTAGE)) * 4) * 512)

    // prime the A register pipeline (in flight during B staging)
    short8 ap[PDEPTH][2];
#pragma unroll
    for (int p = 0; p < PDEPTH; ++p) {
        ap[p][0] = *(const short8*)(Ab + A_OFF(p));
        ap[p][1] = *(const short8*)(Ab + A_OFF(p) + 512);
    }
    __syncthreads();                               // B visible (drains prime loads too; one-time)

    double tk[2][TOPS];
#pragma unroll
    for (int n2 = 0; n2 < 2; ++n2)
#pragma unroll
        for (int j = 0; j < TOPS; ++j) tk[n2][j] = -INFINITY;

    f32x16 zc;
#pragma unroll
    for (int r = 0; r < 16; ++r) zc[r] = 0.f;
    f32x16 acc[2][2];

#pragma unroll
    for (int t = 0; t < NSTEP; ++t) {
        const int s = t % NSTAGE, slot = t % PDEPTH;
        short8 a0 = ap[slot][0], a1 = ap[slot][1];
        if (t + PDEPTH < NSTEP) {                  // refill slot for step t+PDEPTH
            ap[slot][0] = *(const short8*)(Ab + A_OFF(t + PDEPTH));
            ap[slot][1] = *(const short8*)(Ab + A_OFF(t + PDEPTH) + 512);
        }
        short8 b0 = *(const short8*)&Bs[(s * 2 + 0) * 512 + lane * 8];
        short8 b1 = *(const short8*)&Bs[(s * 2 + 1) * 512 + lane * 8];
        __builtin_amdgcn_s_setprio(1);
        if (s == 0) {                              // zero-C MFMA: no explicit acc clears
            acc[0][0] = __builtin_amdgcn_mfma_f32_32x32x16_bf16(a0, b0, zc, 0, 0, 0);
            acc[0][1] = __builtin_amdgcn_mfma_f32_32x32x16_bf16(a0, b1, zc, 0, 0, 0);
            acc[1][0] = __builtin_amdgcn_mfma_f32_32x32x16_bf16(a1, b0, zc, 0, 0, 0);
            acc[1][1] = __builtin_amdgcn_mfma_f32_32x32x16_bf16(a1, b1, zc, 0, 0, 0);
        } else {
            acc[0][0] = __builtin_amdgcn_mfma_f32_32x32x16_bf16(a0, b0, acc[0][0], 0, 0, 0);
            acc[0][1] = __builtin_amdgcn_mfma_f32_32x32x16_bf16(a0, b1, acc[0][1], 0, 0, 0);
            acc[1][0] = __builtin_amdgcn_mfma_f32_32x32x16_bf16(a1, b0, acc[1][0], 0, 0, 0);
            acc[1][1] = __builtin_amdgcn_mfma_f32_32x32x16_bf16(a1, b1, acc[1][1], 0, 0, 0);
        }
        __builtin_amdgcn_s_setprio(0);

        if (s == NSTAGE - 1) {                     // tile done: acc = score/2, norms folded
            const int cb2 = (cs * 8 + (t / NSTAGE) * 2 + th) * 128 + wm * 64 + 4 * h;
#pragma unroll
            for (int mt = 0; mt < 2; ++mt) {
#pragma unroll
                for (int rq = 0; rq < 4; ++rq) {   // quads r = 4rq .. 4rq+3
#pragma unroll
                    for (int n2 = 0; n2 < 2; ++n2) {
                        double q[4];
#pragma unroll
                        for (int i = 0; i < 4; ++i) {
                            const int code = cb2 + mt * 32 + i + 8 * rq;
                            q[i] = mk_key(acc[mt][n2][rq * 4 + i], code);
                        }
                        sort4(q);
                        merge4(q, tk[n2]);
                    }
                }
            }
        }
    }
#undef A_OFF

    __syncthreads();                               // all B reads done before merge aliases B
    const int slot8 = w * 2 + h;                   // 8 cells per query column
#pragma unroll
    for (int n2 = 0; n2 < 2; ++n2) {
        const int ql = n2 * 32 + (lane & 31);
#pragma unroll
        for (int j = 0; j < TOPS; ++j) pks[slot8][ql][j] = tk[n2][j];
    }
    __syncthreads();
    if (tid < 64) {                                // slots are sorted-desc: 7 merge4s
        double mk[TOPS];
#pragma unroll
        for (int j = 0; j < TOPS; ++j) mk[j] = pks[0][tid][j];
#pragma unroll
        for (int sl = 1; sl < 8; ++sl) {
            double q[4];
#pragma unroll
            for (int j = 0; j < TOPS; ++j) q[j] = pks[sl][tid][j];
            merge4(q, mk);
        }
        double4v o;
#pragma unroll
        for (int j = 0; j < TOPS; ++j) o[j] = mk[j];
        *(double4v*)&pkd[((size_t)cs * NQ_TOTAL + qt * 64 + tid) * TOPS] = o;
    }
}

// ---------------------------------------------------------------- candidate merge + exact rescore
__global__ __launch_bounds__(256) void finalize_q(
        const float* __restrict__ X, const float* __restrict__ ET,
        const float* __restrict__ norms, const double* __restrict__ pkd,
        float* __restrict__ outq, float* __restrict__ out_idx_f,
        float* __restrict__ loss_q, int* __restrict__ counts) {
    const int lane = threadIdx.x & 63, w = threadIdx.x >> 6;
    const int q = blockIdx.x * 4 + w;
    float4 x4 = *(const float4*)&X[(size_t)q * DIM + lane * 4];

    double wk = -INFINITY;
    if (lane < 32)
        wk = pkd[(((size_t)(lane >> 2) * NQ_TOTAL + q) * TOPS) + (lane & 3)];

    int kc[8];
#pragma unroll
    for (int t = 0; t < 8; ++t) {
        double m = wk;
#pragma unroll
        for (int o = 1; o < 64; o <<= 1) m = fmax(m, __shfl_xor(m, o));
        kc[t] = (int)(__builtin_bit_cast(unsigned long long, m) & 8191ull);
        if (wk == m) wk = -INFINITY;               // remove winner (keys unique)
    }

    float sb = -FLT_MAX; int kb = 0; float4 eb = x4;
#pragma unroll
    for (int t = 0; t < 8; ++t) {
        int k = kc[t];
        float4 e4 = *(const float4*)&ET[(size_t)k * DIM + lane * 4];
        float pr = x4.x * e4.x + x4.y * e4.y + x4.z * e4.z + x4.w * e4.w;
#pragma unroll
        for (int o = 1; o < 64; o <<= 1) pr += __shfl_xor(pr, o);
        float s = 2.f * pr - norms[k];
        bool better = (s > sb) || (s == sb && k < kb);
        if (better) { sb = s; kb = k; eb = e4; }
    }
    float4 d4 = {eb.x - x4.x, eb.y - x4.y, eb.z - x4.z, eb.w - x4.w};
    float4 o4 = {x4.x + d4.x, x4.y + d4.y, x4.z + d4.z, x4.w + d4.w};
    *(float4*)&outq[(size_t)q * DIM + lane * 4] = o4;
    float l = d4.x * d4.x + d4.y * d4.y + d4.z * d4.z + d4.w * d4.w;
#pragma unroll
    for (int o = 1; o < 64; o <<= 1) l += __shfl_xor(l, o);
    if (lane == 0) {
        out_idx_f[q] = (float)kb;
        loss_q[q] = l;
        atomicAdd(&counts[kb], 1);
    }
}

// ---------------------------------------------------------------- scalars
__global__ __launch_bounds__(256) void final_scalars(
        const int* __restrict__ counts, const float* __restrict__ loss_q,
        float* __restrict__ out_sc) {
    int t = threadIdx.x;
    float ls = 0.f;
    for (int i = t; i < NQ_TOTAL; i += 256) ls += loss_q[i];
    float ent = 0.f;
    for (int k = t; k < K_CODES; k += 256) {
        float p = (float)counts[k] / (float)NQ_TOTAL;
        ent -= p * logf(p + 1e-10f);
    }
#pragma unroll
    for (int o = 1; o < 64; o <<= 1) { ls += __shfl_xor(ls, o); ent += __shfl_xor(ent, o); }
    __shared__ float rl[4], re[4];
    if ((t & 63) == 0) { rl[t >> 6] = ls; re[t >> 6] = ent; }
    __syncthreads();
    if (t == 0) {
        float L = rl[0] + rl[1] + rl[2] + rl[3];
        float Ee = re[0] + re[1] + re[2] + re[3];
        float mse = L / (float)((size_t)NQ_TOTAL * DIM);
        out_sc[0] = 1.1f * mse;                         // e_latent + 0.1*q_latent
        out_sc[1] = -0.1f * (Ee / logf((float)K_CODES));
    }
}

extern "C" void kernel_launch(void* const* d_in, const int* in_sizes, int n_in,
                              void* d_out, int out_size, void* d_ws, size_t ws_size,
                              hipStream_t stream) {
    const float* X = (const float*)d_in[0];   // [32768, 256] fp32
    const float* E = (const float*)d_in[1];   // [256, 8192]  fp32

    float* out       = (float*)d_out;
    float* outq      = out;                           // 8388608
    float* out_idx_f = out + (size_t)NQ_TOTAL * DIM;  // 32768 (indices as f32)
    float* out_sc    = out_idx_f + NQ_TOTAL;          // 2 scalars

    char* ws = (char*)d_ws;
    int*            counts = (int*)(ws + WS_COUNTS);
    float*          loss_q = (float*)(ws + WS_LOSSQ);
    float*          norms  = (float*)(ws + WS_NORMS);
    double*         pkd    = (double*)(ws + WS_PKD);
    float*          ET     = (float*)(ws + WS_ET);
    unsigned short* Ahi    = (unsigned short*)(ws + WS_AHI);
    unsigned short* Bhi    = (unsigned short*)(ws + WS_BHI);

    hipMemsetAsync(counts, 0, K_CODES * sizeof(int), stream);
    prep_E<<<K_CODES / 32, 256, 0, stream>>>(E, Ahi, ET, norms);
    pack_XB<<<XBLOCKS + 256, 256, 0, stream>>>(X, Bhi);
    argmax_mfma<<<dim3(CSPLIT, NQ_TOTAL / 64), 256, 0, stream>>>(Ahi, Bhi, pkd);
    finalize_q<<<NQ_TOTAL / 4, 256, 0, stream>>>(X, ET, norms, pkd, outq, out_idx_f, loss_q, counts);
    final_scalars<<<1, 256, 0, stream>>>(counts, loss_q, out_sc);
}

// Round 9
// 369.942 us; speedup vs baseline: 1.1539x; 1.0185x over previous
//
#include <hip/hip_runtime.h>
#include <cfloat>
#include <cmath>

typedef short short8 __attribute__((ext_vector_type(8)));
typedef unsigned short ushort8 __attribute__((ext_vector_type(8)));
typedef float f32x16 __attribute__((ext_vector_type(16)));
typedef double double4v __attribute__((ext_vector_type(4)));

#define K_CODES 8192
#define DIM 256
#define NQ_TOTAL 32768
#define CSPLIT 8
#define NSTAGE 17          /* 16 data stages + 1 norm stage */
#define NSTEP 68           /* 4 double-tiles (256 codes) x 17 stages */
#define PDEPTH 4           /* A-pipeline depth */
#define TOPS 4             /* per-slice top-N stored */

/* ws layout (byte offsets) — identical to R4/R8 */
#define WS_COUNTS 0          /* int[8192]            32 KB (zeroed) */
#define WS_LOSSQ  32768      /* float[32768]        128 KB */
#define WS_NORMS  163840     /* float[8192]          32 KB */
#define WS_PKD    196608     /* double[8*32768*4]     8 MB */
#define WS_ET     8585216    /* float[8192*256]       8 MB */
#define WS_AHI    16973824   /* ushort[64*17*4*64*8]  4.25 MB */
#define WS_BHI    21430272   /* ushort[512*17*2*64*8] 17 MB */

__device__ inline unsigned short f32_to_bf16_rne(float x) {
    unsigned u = __builtin_bit_cast(unsigned, x);
    unsigned r = u + 0x7FFFu + ((u >> 16) & 1u);
    return (unsigned short)(r >> 16);
}
__device__ inline float bf16_to_f32(unsigned short hh) {
    unsigned u = ((unsigned)hh) << 16;
    return __builtin_bit_cast(float, u);
}

// SYNTHETIC f64 key (R9): high dword = raw f32 score bits, low dword = code.
// No cvt needed. Ordering: for same-sign f32s the f64 formed this way orders
// exactly like the f32 (high dword = sign+exp+mantissa prefix dominates); all
// scores here are negative (-0.5*||x-e||^2), and distinct f32 scores differ in
// the high dword -> score comparison is BIT-EXACT. Code bits (low dword) only
// break exact-score ties (deterministic; exact ties vs reference are resolved
// by the fp32 rescore's k<kb tiebreak, as in R4/R8). Scores can never be NaN
// and |score|>=2^-104 in practice -> no denormal-f64 edge (f64 denorms are
// full-rate IEEE on CDNA anyway).
__device__ inline double mk_key(float v, int code) {
    unsigned long long b = ((unsigned long long)__builtin_bit_cast(unsigned, v) << 32)
                         | (unsigned long long)(unsigned)code;
    return __builtin_bit_cast(double, b);
}

// compare-exchange (descending): a=max, b=min — v_max_f64 + v_min_f64
__device__ inline void ced(double& a, double& b) {
    double hi = fmax(a, b), lo = fmin(a, b);
    a = hi; b = lo;
}
// full descending sort of 4 keys (5-CE network)
__device__ inline void sort4(double* q) {
    ced(q[0], q[1]); ced(q[2], q[3]); ced(q[0], q[2]); ced(q[1], q[3]); ced(q[1], q[2]);
}
// EXACT top-4 of (sorted-desc q[4], sorted-desc tk[4]) -> tk sorted-desc.
// Odd-even merge identity: top4 set = { max(q[i], tk[3-i]) }; result is
// bitonic -> 4-CE cleanup. 12 ops vs 32 for 4 ladder inserts.
__device__ inline void merge4(const double* q, double* tk) {
    double t0 = fmax(q[0], tk[3]);
    double t1 = fmax(q[1], tk[2]);
    double t2 = fmax(q[2], tk[1]);
    double t3 = fmax(q[3], tk[0]);
    ced(t0, t2); ced(t1, t3); ced(t0, t1); ced(t2, t3);
    tk[0] = t0; tk[1] = t1; tk[2] = t2; tk[3] = t3;
}

// ---------------------------------------------------------------- fused E prep
__global__ __launch_bounds__(256) void prep_E(const float* __restrict__ E,
                                              unsigned short* __restrict__ Ahi,
                                              float* __restrict__ ET,
                                              float* __restrict__ norms) {
    __shared__ float part[8][32];
    const int tid = threadIdx.x;
    const int cl = tid & 31, g = tid >> 5;        // g in 0..7
    const int c0 = blockIdx.x * 32;               // 256 blocks
    const int c = c0 + cl;
    float ssum = 0.f;
#pragma unroll
    for (int i = 0; i < 4; ++i) {
        const int db = g + 8 * i;                 // db in 0..31 (8 dims each)
        float xs[8];
#pragma unroll
        for (int j = 0; j < 8; ++j) {
            xs[j] = E[(size_t)(db * 8 + j) * K_CODES + c];
            ssum += xs[j] * xs[j];
        }
        float4 f0 = {xs[0], xs[1], xs[2], xs[3]}, f1 = {xs[4], xs[5], xs[6], xs[7]};
        *(float4*)&ET[(size_t)c * DIM + db * 8]     = f0;
        *(float4*)&ET[(size_t)c * DIM + db * 8 + 4] = f1;
        ushort8 vh;
#pragma unroll
        for (int j = 0; j < 8; ++j) vh[j] = f32_to_bf16_rne(xs[j]);
        const int ct = c >> 7, mt = (c >> 5) & 3, lc = c & 31, s = db >> 1, hh = db & 1;
        const int lane2 = lc + 32 * hh;
        size_t chunk = ((((size_t)ct * NSTAGE + s) * 4 + mt) * 64 + lane2) * 8;
        *(ushort8*)&Ahi[chunk] = vh;
    }
    part[g][cl] = ssum;
    __syncthreads();
    if (tid < 64) {                               // A norm-stage chunk for this (ct, mt)
        const int ct = c0 >> 7, mt = (c0 >> 5) & 3;
        ushort8 v = {0, 0, 0, 0, 0, 0, 0, 0};
        if (tid < 32) {
            float nrm = 0.f;
#pragma unroll
            for (int gg = 0; gg < 8; ++gg) nrm += part[gg][tid];
            norms[c0 + tid] = nrm;
            unsigned short hi = f32_to_bf16_rne(nrm);
            unsigned short lo = f32_to_bf16_rne(nrm - bf16_to_f32(hi));
            v[0] = hi; v[1] = lo;
        }
        size_t chunk = ((((size_t)ct * NSTAGE + 16) * 4 + mt) * 64 + tid) * 8;
        *(ushort8*)&Ahi[chunk] = v;
    }
}

// ---------------------------------------------------------------- pack X -> frag-linear bf16
// blocks [0, 4096): X data stages; blocks [4096, 4352): B norm-stage constants.
#define XBLOCKS 4096
__global__ __launch_bounds__(256) void pack_XB(const float* __restrict__ X,
                                               unsigned short* __restrict__ Bhi) {
    const int bid = blockIdx.x;
    if (bid >= XBLOCKS) {                         // B norm-stage: -0.5 at k=0,1
        int id = (bid - XBLOCKS) * 256 + threadIdx.x;   // 65536 total
        int lane = id & 63, nt = (id >> 6) & 1, qt = id >> 7;
        ushort8 v = {0, 0, 0, 0, 0, 0, 0, 0};
        if (lane < 32) { v[0] = 0xBF00; v[1] = 0xBF00; }   // bf16(-0.5)
        size_t chunk = ((((size_t)qt * NSTAGE + 16) * 2 + nt) * 64 + lane) * 8;
        *(ushort8*)&Bhi[chunk] = v;
        return;
    }
    int id = bid * 256 + threadIdx.x;             // 1048576 total
    int q = id >> 5, db = id & 31;
    const float* src = X + (size_t)q * DIM + db * 8;
    float4 a = *(const float4*)src, b = *(const float4*)(src + 4);
    float xs[8] = {a.x, a.y, a.z, a.w, b.x, b.y, b.z, b.w};
    ushort8 vh;
#pragma unroll
    for (int i = 0; i < 8; ++i) vh[i] = f32_to_bf16_rne(xs[i]);
    int qt = q >> 6, nt = (q >> 5) & 1, lq = q & 31, s = db >> 1, hh = db & 1;
    int lane = lq + 32 * hh;
    size_t chunk = ((((size_t)qt * NSTAGE + s) * 2 + nt) * 64 + lane) * 8;
    *(ushort8*)&Bhi[chunk] = vh;
}

// ---------------------------------------------------------------- MFMA argmax — barrier-free K-loop
// R9 = R8 + (a) synthetic f64 keys (no cvt: key = {f32 bits, code} reg pair),
// (b) readfirstlane-scalarized A-stream base: A address = SGPR base +
// compile-time per-step constant + lane*16 VGPR -> saddr-form loads, address
// adds move from VALU to SALU. Selection semantics identical to R8.
__global__ __launch_bounds__(256, 3) void argmax_mfma(
        const unsigned short* __restrict__ Ahi, const unsigned short* __restrict__ Bhi,
        double* __restrict__ pkd) {
    __shared__ __align__(16) char smem[34816];                 // B: 17*2*512 shorts
    unsigned short* Bs = (unsigned short*)smem;
    double (*pks)[64][TOPS] = (double (*)[64][TOPS])smem;      // merge aliases B (16 KB)

    const int tid = threadIdx.x;
    const int lane = tid & 63, w = tid >> 6;
    const int th = w >> 1, wm = w & 1;             // tile-half, chunk-pair
    const int h = lane >> 5;
    const int cs = blockIdx.x, qt = blockIdx.y;

    // ---- stage B once: 34 x 1KB chunks (wave-strided)
#pragma unroll
    for (int i = 0; i < 9; ++i) {
        const int g = w + 4 * i;
        if (g < 34) {
            const unsigned short* src = Bhi + (((size_t)qt * 34 + g) * 64 + lane) * 8;
            __builtin_amdgcn_global_load_lds(
                (const __attribute__((address_space(1))) unsigned int*)src,
                (__attribute__((address_space(3))) unsigned int*)(Bs + g * 512), 16, 0, 0);
        }
    }

    // ---- A stream: byte address = base(cs, th, wm) [wave-uniform -> SGPR via
    // readfirstlane] + ((t/17)*34 + t%17)*4096 [compile-time] + lane*16 [VGPR].
    // Equivalent to R8's A_OFF: ((cs*8+(t/17)*2+th)*17 + t%17)*4096 + wm*2048.
    unsigned long long ab64 = (unsigned long long)(uintptr_t)Ahi
        + (unsigned long long)((unsigned)cs * (8u * 17u * 4096u))
        + (unsigned long long)(unsigned)(th * (17 * 4096) + wm * 2048);
    unsigned ab_lo = __builtin_amdgcn_readfirstlane((unsigned)ab64);
    unsigned ab_hi = __builtin_amdgcn_readfirstlane((unsigned)(ab64 >> 32));
    const char* Asb = (const char*)(uintptr_t)(((unsigned long long)ab_hi << 32) | ab_lo);
    const unsigned lane16 = (unsigned)lane * 16u;
#define A_BYT(t) ((size_t)((((t) / NSTAGE) * 34) + ((t) % NSTAGE)) * 4096)

    // prime the A register pipeline (in flight during B staging)
    short8 ap[PDEPTH][2];
#pragma unroll
    for (int p = 0; p < PDEPTH; ++p) {
        ap[p][0] = *(const short8*)(Asb + A_BYT(p) + lane16);
        ap[p][1] = *(const short8*)(Asb + A_BYT(p) + 1024 + lane16);
    }
    __syncthreads();                               // B visible (drains prime loads too; one-time)

    double tk[2][TOPS];
#pragma unroll
    for (int n2 = 0; n2 < 2; ++n2)
#pragma unroll
        for (int j = 0; j < TOPS; ++j) tk[n2][j] = -INFINITY;

    f32x16 zc;
#pragma unroll
    for (int r = 0; r < 16; ++r) zc[r] = 0.f;
    f32x16 acc[2][2];

#pragma unroll
    for (int t = 0; t < NSTEP; ++t) {
        const int s = t % NSTAGE, slot = t % PDEPTH;
        short8 a0 = ap[slot][0], a1 = ap[slot][1];
        if (t + PDEPTH < NSTEP) {                  // refill slot for step t+PDEPTH
            ap[slot][0] = *(const short8*)(Asb + A_BYT(t + PDEPTH) + lane16);
            ap[slot][1] = *(const short8*)(Asb + A_BYT(t + PDEPTH) + 1024 + lane16);
        }
        short8 b0 = *(const short8*)&Bs[(s * 2 + 0) * 512 + lane * 8];
        short8 b1 = *(const short8*)&Bs[(s * 2 + 1) * 512 + lane * 8];
        __builtin_amdgcn_s_setprio(1);
        if (s == 0) {                              // zero-C MFMA: no explicit acc clears
            acc[0][0] = __builtin_amdgcn_mfma_f32_32x32x16_bf16(a0, b0, zc, 0, 0, 0);
            acc[0][1] = __builtin_amdgcn_mfma_f32_32x32x16_bf16(a0, b1, zc, 0, 0, 0);
            acc[1][0] = __builtin_amdgcn_mfma_f32_32x32x16_bf16(a1, b0, zc, 0, 0, 0);
            acc[1][1] = __builtin_amdgcn_mfma_f32_32x32x16_bf16(a1, b1, zc, 0, 0, 0);
        } else {
            acc[0][0] = __builtin_amdgcn_mfma_f32_32x32x16_bf16(a0, b0, acc[0][0], 0, 0, 0);
            acc[0][1] = __builtin_amdgcn_mfma_f32_32x32x16_bf16(a0, b1, acc[0][1], 0, 0, 0);
            acc[1][0] = __builtin_amdgcn_mfma_f32_32x32x16_bf16(a1, b0, acc[1][0], 0, 0, 0);
            acc[1][1] = __builtin_amdgcn_mfma_f32_32x32x16_bf16(a1, b1, acc[1][1], 0, 0, 0);
        }
        __builtin_amdgcn_s_setprio(0);

        if (s == NSTAGE - 1) {                     // tile done: acc = score/2, norms folded
            const int cb2 = (cs * 8 + (t / NSTAGE) * 2 + th) * 128 + wm * 64 + 4 * h;
#pragma unroll
            for (int mt = 0; mt < 2; ++mt) {
#pragma unroll
                for (int rq = 0; rq < 4; ++rq) {   // quads r = 4rq .. 4rq+3
#pragma unroll
                    for (int n2 = 0; n2 < 2; ++n2) {
                        double q[4];
#pragma unroll
                        for (int i = 0; i < 4; ++i) {
                            const int code = cb2 + mt * 32 + i + 8 * rq;
                            q[i] = mk_key(acc[mt][n2][rq * 4 + i], code);
                        }
                        sort4(q);
                        merge4(q, tk[n2]);
                    }
                }
            }
        }
    }
#undef A_BYT

    __syncthreads();                               // all B reads done before merge aliases B
    const int slot8 = w * 2 + h;                   // 8 cells per query column
#pragma unroll
    for (int n2 = 0; n2 < 2; ++n2) {
        const int ql = n2 * 32 + (lane & 31);
#pragma unroll
        for (int j = 0; j < TOPS; ++j) pks[slot8][ql][j] = tk[n2][j];
    }
    __syncthreads();
    if (tid < 64) {                                // slots are sorted-desc: 7 merge4s
        double mk[TOPS];
#pragma unroll
        for (int j = 0; j < TOPS; ++j) mk[j] = pks[0][tid][j];
#pragma unroll
        for (int sl = 1; sl < 8; ++sl) {
            double q[4];
#pragma unroll
            for (int j = 0; j < TOPS; ++j) q[j] = pks[sl][tid][j];
            merge4(q, mk);
        }
        double4v o;
#pragma unroll
        for (int j = 0; j < TOPS; ++j) o[j] = mk[j];
        *(double4v*)&pkd[((size_t)cs * NQ_TOTAL + qt * 64 + tid) * TOPS] = o;
    }
}

// ---------------------------------------------------------------- candidate merge + exact rescore
// Keys are synthetic f64s (ordering-preserving; code in low dword) — extraction
// and code recovery unchanged vs R8.
__global__ __launch_bounds__(256) void finalize_q(
        const float* __restrict__ X, const float* __restrict__ ET,
        const float* __restrict__ norms, const double* __restrict__ pkd,
        float* __restrict__ outq, float* __restrict__ out_idx_f,
        float* __restrict__ loss_q, int* __restrict__ counts) {
    const int lane = threadIdx.x & 63, w = threadIdx.x >> 6;
    const int q = blockIdx.x * 4 + w;
    float4 x4 = *(const float4*)&X[(size_t)q * DIM + lane * 4];

    double wk = -INFINITY;
    if (lane < 32)
        wk = pkd[(((size_t)(lane >> 2) * NQ_TOTAL + q) * TOPS) + (lane & 3)];

    int kc[8];
#pragma unroll
    for (int t = 0; t < 8; ++t) {
        double m = wk;
#pragma unroll
        for (int o = 1; o < 64; o <<= 1) m = fmax(m, __shfl_xor(m, o));
        kc[t] = (int)(__builtin_bit_cast(unsigned long long, m) & 8191ull);
        if (wk == m) wk = -INFINITY;               // remove winner (keys unique)
    }

    float sb = -FLT_MAX; int kb = 0; float4 eb = x4;
#pragma unroll
    for (int t = 0; t < 8; ++t) {
        int k = kc[t];
        float4 e4 = *(const float4*)&ET[(size_t)k * DIM + lane * 4];
        float pr = x4.x * e4.x + x4.y * e4.y + x4.z * e4.z + x4.w * e4.w;
#pragma unroll
        for (int o = 1; o < 64; o <<= 1) pr += __shfl_xor(pr, o);
        float s = 2.f * pr - norms[k];
        bool better = (s > sb) || (s == sb && k < kb);
        if (better) { sb = s; kb = k; eb = e4; }
    }
    float4 d4 = {eb.x - x4.x, eb.y - x4.y, eb.z - x4.z, eb.w - x4.w};
    float4 o4 = {x4.x + d4.x, x4.y + d4.y, x4.z + d4.z, x4.w + d4.w};
    *(float4*)&outq[(size_t)q * DIM + lane * 4] = o4;
    float l = d4.x * d4.x + d4.y * d4.y + d4.z * d4.z + d4.w * d4.w;
#pragma unroll
    for (int o = 1; o < 64; o <<= 1) l += __shfl_xor(l, o);
    if (lane == 0) {
        out_idx_f[q] = (float)kb;
        loss_q[q] = l;
        atomicAdd(&counts[kb], 1);
    }
}

// ---------------------------------------------------------------- scalars
__global__ __launch_bounds__(256) void final_scalars(
        const int* __restrict__ counts, const float* __restrict__ loss_q,
        float* __restrict__ out_sc) {
    int t = threadIdx.x;
    float ls = 0.f;
    for (int i = t; i < NQ_TOTAL; i += 256) ls += loss_q[i];
    float ent = 0.f;
    for (int k = t; k < K_CODES; k += 256) {
        float p = (float)counts[k] / (float)NQ_TOTAL;
        ent -= p * logf(p + 1e-10f);
    }
#pragma unroll
    for (int o = 1; o < 64; o <<= 1) { ls += __shfl_xor(ls, o); ent += __shfl_xor(ent, o); }
    __shared__ float rl[4], re[4];
    if ((t & 63) == 0) { rl[t >> 6] = ls; re[t >> 6] = ent; }
    __syncthreads();
    if (t == 0) {
        float L = rl[0] + rl[1] + rl[2] + rl[3];
        float Ee = re[0] + re[1] + re[2] + re[3];
        float mse = L / (float)((size_t)NQ_TOTAL * DIM);
        out_sc[0] = 1.1f * mse;                         // e_latent + 0.1*q_latent
        out_sc[1] = -0.1f * (Ee / logf((float)K_CODES));
    }
}

extern "C" void kernel_launch(void* const* d_in, const int* in_sizes, int n_in,
                              void* d_out, int out_size, void* d_ws, size_t ws_size,
                              hipStream_t stream) {
    const float* X = (const float*)d_in[0];   // [32768, 256] fp32
    const float* E = (const float*)d_in[1];   // [256, 8192]  fp32

    float* out       = (float*)d_out;
    float* outq      = out;                           // 8388608
    float* out_idx_f = out + (size_t)NQ_TOTAL * DIM;  // 32768 (indices as f32)
    float* out_sc    = out_idx_f + NQ_TOTAL;          // 2 scalars

    char* ws = (char*)d_ws;
    int*            counts = (int*)(ws + WS_COUNTS);
    float*          loss_q = (float*)(ws + WS_LOSSQ);
    float*          norms  = (float*)(ws + WS_NORMS);
    double*         pkd    = (double*)(ws + WS_PKD);
    float*          ET     = (float*)(ws + WS_ET);
    unsigned short* Ahi    = (unsigned short*)(ws + WS_AHI);
    unsigned short* Bhi    = (unsigned short*)(ws + WS_BHI);

    hipMemsetAsync(counts, 0, K_CODES * sizeof(int), stream);
    prep_E<<<K_CODES / 32, 256, 0, stream>>>(E, Ahi, ET, norms);
    pack_XB<<<XBLOCKS + 256, 256, 0, stream>>>(X, Bhi);
    argmax_mfma<<<dim3(CSPLIT, NQ_TOTAL / 64), 256, 0, stream>>>(Ahi, Bhi, pkd);
    finalize_q<<<NQ_TOTAL / 4, 256, 0, stream>>>(X, ET, norms, pkd, outq, out_idx_f, loss_q, counts);
    final_scalars<<<1, 256, 0, stream>>>(counts, loss_q, out_sc);
}

// Round 10
// 368.801 us; speedup vs baseline: 1.1575x; 1.0031x over previous
//
#include <hip/hip_runtime.h>
#include <cfloat>
#include <cmath>

typedef short short8 __attribute__((ext_vector_type(8)));
typedef unsigned short ushort8 __attribute__((ext_vector_type(8)));
typedef float f32x16 __attribute__((ext_vector_type(16)));
typedef double double4v __attribute__((ext_vector_type(4)));

#define K_CODES 8192
#define DIM 256
#define NQ_TOTAL 32768
#define CSPLIT 8
#define NSTAGE 17          /* 16 data stages + 1 norm stage */
#define NSTEP 68           /* 4 double-tiles (256 codes) x 17 stages */
#define PDEPTH 4           /* A-pipeline depth */
#define TOPS 4             /* per-slice top-N stored */

/* ws layout (byte offsets) — identical to R4/R8/R9 */
#define WS_COUNTS 0          /* int[8192]            32 KB (zeroed) */
#define WS_LOSSQ  32768      /* float[32768]        128 KB */
#define WS_NORMS  163840     /* float[8192]          32 KB */
#define WS_PKD    196608     /* double[8*32768*4]     8 MB */
#define WS_ET     8585216    /* float[8192*256]       8 MB */
#define WS_AHI    16973824   /* ushort[64*17*4*64*8]  4.25 MB */
#define WS_BHI    21430272   /* ushort[512*17*2*64*8] 17 MB */

__device__ inline unsigned short f32_to_bf16_rne(float x) {
    unsigned u = __builtin_bit_cast(unsigned, x);
    unsigned r = u + 0x7FFFu + ((u >> 16) & 1u);
    return (unsigned short)(r >> 16);
}
__device__ inline float bf16_to_f32(unsigned short hh) {
    unsigned u = ((unsigned)hh) << 16;
    return __builtin_bit_cast(float, u);
}

// SYNTHETIC f64 key: high dword = raw f32 score bits, low dword = code.
// For same-sign f32s (scores are all negative: -0.5*||x-e||^2) the f64 formed
// this way orders exactly like the f32; distinct scores differ in the high
// dword -> score compare is BIT-EXACT; code bits only break exact-score ties.
__device__ inline double mk_key(float v, int code) {
    unsigned long long b = ((unsigned long long)__builtin_bit_cast(unsigned, v) << 32)
                         | (unsigned long long)(unsigned)code;
    return __builtin_bit_cast(double, b);
}

// compare-exchange (descending): a=max, b=min — v_max_f64 + v_min_f64
__device__ inline void ced(double& a, double& b) {
    double hi = fmax(a, b), lo = fmin(a, b);
    a = hi; b = lo;
}
// full descending sort of 4 keys (5-CE network)
__device__ inline void sort4(double* q) {
    ced(q[0], q[1]); ced(q[2], q[3]); ced(q[0], q[2]); ced(q[1], q[3]); ced(q[1], q[2]);
}
// EXACT top-4 of (sorted-desc q[4], sorted-desc tk[4]) -> tk sorted-desc.
// Odd-even merge identity: top4 set = { max(q_i, tk_{3-i}) }; result is
// bitonic -> 4-CE cleanup. 12 ops vs 32 for 4 ladder inserts.
__device__ inline void merge4(const double* q, double* tk) {
    double t0 = fmax(q[0], tk[3]);
    double t1 = fmax(q[1], tk[2]);
    double t2 = fmax(q[2], tk[1]);
    double t3 = fmax(q[3], tk[0]);
    ced(t0, t2); ced(t1, t3); ced(t0, t1); ced(t2, t3);
    tk[0] = t0; tk[1] = t1; tk[2] = t2; tk[3] = t3;
}

// ---------------------------------------------------------------- fused E prep
__global__ __launch_bounds__(256) void prep_E(const float* __restrict__ E,
                                              unsigned short* __restrict__ Ahi,
                                              float* __restrict__ ET,
                                              float* __restrict__ norms) {
    __shared__ float part[8][32];
    const int tid = threadIdx.x;
    const int cl = tid & 31, g = tid >> 5;        // g in 0..7
    const int c0 = blockIdx.x * 32;               // 256 blocks
    const int c = c0 + cl;
    float ssum = 0.f;
#pragma unroll
    for (int i = 0; i < 4; ++i) {
        const int db = g + 8 * i;                 // db in 0..31 (8 dims each)
        float xs[8];
#pragma unroll
        for (int j = 0; j < 8; ++j) {
            xs[j] = E[(size_t)(db * 8 + j) * K_CODES + c];
            ssum += xs[j] * xs[j];
        }
        float4 f0 = {xs[0], xs[1], xs[2], xs[3]}, f1 = {xs[4], xs[5], xs[6], xs[7]};
        *(float4*)&ET[(size_t)c * DIM + db * 8]     = f0;
        *(float4*)&ET[(size_t)c * DIM + db * 8 + 4] = f1;
        ushort8 vh;
#pragma unroll
        for (int j = 0; j < 8; ++j) vh[j] = f32_to_bf16_rne(xs[j]);
        const int ct = c >> 7, mt = (c >> 5) & 3, lc = c & 31, s = db >> 1, hh = db & 1;
        const int lane2 = lc + 32 * hh;
        size_t chunk = ((((size_t)ct * NSTAGE + s) * 4 + mt) * 64 + lane2) * 8;
        *(ushort8*)&Ahi[chunk] = vh;
    }
    part[g][cl] = ssum;
    __syncthreads();
    if (tid < 64) {                               // A norm-stage chunk for this (ct, mt)
        const int ct = c0 >> 7, mt = (c0 >> 5) & 3;
        ushort8 v = {0, 0, 0, 0, 0, 0, 0, 0};
        if (tid < 32) {
            float nrm = 0.f;
#pragma unroll
            for (int gg = 0; gg < 8; ++gg) nrm += part[gg][tid];
            norms[c0 + tid] = nrm;
            unsigned short hi = f32_to_bf16_rne(nrm);
            unsigned short lo = f32_to_bf16_rne(nrm - bf16_to_f32(hi));
            v[0] = hi; v[1] = lo;
        }
        size_t chunk = ((((size_t)ct * NSTAGE + 16) * 4 + mt) * 64 + tid) * 8;
        *(ushort8*)&Ahi[chunk] = v;
    }
}

// ---------------------------------------------------------------- pack X -> frag-linear bf16
// blocks [0, 4096): X data stages; blocks [4096, 4352): B norm-stage constants.
#define XBLOCKS 4096
__global__ __launch_bounds__(256) void pack_XB(const float* __restrict__ X,
                                               unsigned short* __restrict__ Bhi) {
    const int bid = blockIdx.x;
    if (bid >= XBLOCKS) {                         // B norm-stage: -0.5 at k=0,1
        int id = (bid - XBLOCKS) * 256 + threadIdx.x;   // 65536 total
        int lane = id & 63, nt = (id >> 6) & 1, qt = id >> 7;
        ushort8 v = {0, 0, 0, 0, 0, 0, 0, 0};
        if (lane < 32) { v[0] = 0xBF00; v[1] = 0xBF00; }   // bf16(-0.5)
        size_t chunk = ((((size_t)qt * NSTAGE + 16) * 2 + nt) * 64 + lane) * 8;
        *(ushort8*)&Bhi[chunk] = v;
        return;
    }
    int id = bid * 256 + threadIdx.x;             // 1048576 total
    int q = id >> 5, db = id & 31;
    const float* src = X + (size_t)q * DIM + db * 8;
    float4 a = *(const float4*)src, b = *(const float4*)(src + 4);
    float xs[8] = {a.x, a.y, a.z, a.w, b.x, b.y, b.z, b.w};
    ushort8 vh;
#pragma unroll
    for (int i = 0; i < 8; ++i) vh[i] = f32_to_bf16_rne(xs[i]);
    int qt = q >> 6, nt = (q >> 5) & 1, lq = q & 31, s = db >> 1, hh = db & 1;
    int lane = lq + 32 * hh;
    size_t chunk = ((((size_t)qt * NSTAGE + s) * 2 + nt) * 64 + lane) * 8;
    *(ushort8*)&Bhi[chunk] = vh;
}

// ---------------------------------------------------------------- MFMA argmax — barrier-free K-loop
// R10 = R9 + wave skew. Counters show MfmaUtil⊂VALUBusy and total busy ~50%:
// waves are phase-locked (post-staging syncthreads aligns identical streams),
// so all 3 resident waves/SIMD scan simultaneously (matrix idle) and MFMA
// simultaneously (VALU idle). Skew wave w by w*1024 cyc so phases interleave
// and the scheduler can co-execute MFMA and scan across waves (m114 mechanism).
__global__ __launch_bounds__(256, 3) void argmax_mfma(
        const unsigned short* __restrict__ Ahi, const unsigned short* __restrict__ Bhi,
        double* __restrict__ pkd) {
    __shared__ __align__(16) char smem[34816];                 // B: 17*2*512 shorts
    unsigned short* Bs = (unsigned short*)smem;
    double (*pks)[64][TOPS] = (double (*)[64][TOPS])smem;      // merge aliases B (16 KB)

    const int tid = threadIdx.x;
    const int lane = tid & 63, w = tid >> 6;
    const int th = w >> 1, wm = w & 1;             // tile-half, chunk-pair
    const int h = lane >> 5;
    const int cs = blockIdx.x, qt = blockIdx.y;

    // ---- stage B once: 34 x 1KB chunks (wave-strided)
#pragma unroll
    for (int i = 0; i < 9; ++i) {
        const int g = w + 4 * i;
        if (g < 34) {
            const unsigned short* src = Bhi + (((size_t)qt * 34 + g) * 64 + lane) * 8;
            __builtin_amdgcn_global_load_lds(
                (const __attribute__((address_space(1))) unsigned int*)src,
                (__attribute__((address_space(3))) unsigned int*)(Bs + g * 512), 16, 0, 0);
        }
    }

    // ---- A stream: byte address = base(cs, th, wm) [wave-uniform -> SGPR via
    // readfirstlane] + ((t/17)*34 + t%17)*4096 [compile-time] + lane*16 [VGPR].
    unsigned long long ab64 = (unsigned long long)(uintptr_t)Ahi
        + (unsigned long long)((unsigned)cs * (8u * 17u * 4096u))
        + (unsigned long long)(unsigned)(th * (17 * 4096) + wm * 2048);
    unsigned ab_lo = __builtin_amdgcn_readfirstlane((unsigned)ab64);
    unsigned ab_hi = __builtin_amdgcn_readfirstlane((unsigned)(ab64 >> 32));
    const char* Asb = (const char*)(uintptr_t)(((unsigned long long)ab_hi << 32) | ab_lo);
    const unsigned lane16 = (unsigned)lane * 16u;
#define A_BYT(t) ((size_t)((((t) / NSTAGE) * 34) + ((t) % NSTAGE)) * 4096)

    // prime the A register pipeline (in flight during B staging)
    short8 ap[PDEPTH][2];
#pragma unroll
    for (int p = 0; p < PDEPTH; ++p) {
        ap[p][0] = *(const short8*)(Asb + A_BYT(p) + lane16);
        ap[p][1] = *(const short8*)(Asb + A_BYT(p) + 1024 + lane16);
    }
    __syncthreads();                               // B visible (drains prime loads too; one-time)

    // ---- de-phase the waves: wave w sleeps ~w*1024 cycles (s_sleep(4)=256cy).
    // One-time cost <=3k cyc; breaks the scan/MFMA phase-lock for the whole loop.
#pragma unroll
    for (int i = 0; i < 12; ++i)
        if (i < w * 4) __builtin_amdgcn_s_sleep(4);

    double tk[2][TOPS];
#pragma unroll
    for (int n2 = 0; n2 < 2; ++n2)
#pragma unroll
        for (int j = 0; j < TOPS; ++j) tk[n2][j] = -INFINITY;

    f32x16 zc;
#pragma unroll
    for (int r = 0; r < 16; ++r) zc[r] = 0.f;
    f32x16 acc[2][2];

#pragma unroll
    for (int t = 0; t < NSTEP; ++t) {
        const int s = t % NSTAGE, slot = t % PDEPTH;
        short8 a0 = ap[slot][0], a1 = ap[slot][1];
        if (t + PDEPTH < NSTEP) {                  // refill slot for step t+PDEPTH
            ap[slot][0] = *(const short8*)(Asb + A_BYT(t + PDEPTH) + lane16);
            ap[slot][1] = *(const short8*)(Asb + A_BYT(t + PDEPTH) + 1024 + lane16);
        }
        short8 b0 = *(const short8*)&Bs[(s * 2 + 0) * 512 + lane * 8];
        short8 b1 = *(const short8*)&Bs[(s * 2 + 1) * 512 + lane * 8];
        __builtin_amdgcn_s_setprio(1);
        if (s == 0) {                              // zero-C MFMA: no explicit acc clears
            acc[0][0] = __builtin_amdgcn_mfma_f32_32x32x16_bf16(a0, b0, zc, 0, 0, 0);
            acc[0][1] = __builtin_amdgcn_mfma_f32_32x32x16_bf16(a0, b1, zc, 0, 0, 0);
            acc[1][0] = __builtin_amdgcn_mfma_f32_32x32x16_bf16(a1, b0, zc, 0, 0, 0);
            acc[1][1] = __builtin_amdgcn_mfma_f32_32x32x16_bf16(a1, b1, zc, 0, 0, 0);
        } else {
            acc[0][0] = __builtin_amdgcn_mfma_f32_32x32x16_bf16(a0, b0, acc[0][0], 0, 0, 0);
            acc[0][1] = __builtin_amdgcn_mfma_f32_32x32x16_bf16(a0, b1, acc[0][1], 0, 0, 0);
            acc[1][0] = __builtin_amdgcn_mfma_f32_32x32x16_bf16(a1, b0, acc[1][0], 0, 0, 0);
            acc[1][1] = __builtin_amdgcn_mfma_f32_32x32x16_bf16(a1, b1, acc[1][1], 0, 0, 0);
        }
        __builtin_amdgcn_s_setprio(0);

        if (s == NSTAGE - 1) {                     // tile done: acc = score/2, norms folded
            const int cb2 = (cs * 8 + (t / NSTAGE) * 2 + th) * 128 + wm * 64 + 4 * h;
#pragma unroll
            for (int mt = 0; mt < 2; ++mt) {
#pragma unroll
                for (int rq = 0; rq < 4; ++rq) {   // quads r = 4rq .. 4rq+3
#pragma unroll
                    for (int n2 = 0; n2 < 2; ++n2) {
                        double q[4];
#pragma unroll
                        for (int i = 0; i < 4; ++i) {
                            const int code = cb2 + mt * 32 + i + 8 * rq;
                            q[i] = mk_key(acc[mt][n2][rq * 4 + i], code);
                        }
                        sort4(q);
                        merge4(q, tk[n2]);
                    }
                }
            }
        }
    }
#undef A_BYT

    __syncthreads();                               // all B reads done before merge aliases B
    const int slot8 = w * 2 + h;                   // 8 cells per query column
#pragma unroll
    for (int n2 = 0; n2 < 2; ++n2) {
        const int ql = n2 * 32 + (lane & 31);
#pragma unroll
        for (int j = 0; j < TOPS; ++j) pks[slot8][ql][j] = tk[n2][j];
    }
    __syncthreads();
    if (tid < 64) {                                // slots are sorted-desc: 7 merge4s
        double mk[TOPS];
#pragma unroll
        for (int j = 0; j < TOPS; ++j) mk[j] = pks[0][tid][j];
#pragma unroll
        for (int sl = 1; sl < 8; ++sl) {
            double q[4];
#pragma unroll
            for (int j = 0; j < TOPS; ++j) q[j] = pks[sl][tid][j];
            merge4(q, mk);
        }
        double4v o;
#pragma unroll
        for (int j = 0; j < TOPS; ++j) o[j] = mk[j];
        *(double4v*)&pkd[((size_t)cs * NQ_TOTAL + qt * 64 + tid) * TOPS] = o;
    }
}

// ---------------------------------------------------------------- candidate merge + exact rescore
__global__ __launch_bounds__(256) void finalize_q(
        const float* __restrict__ X, const float* __restrict__ ET,
        const float* __restrict__ norms, const double* __restrict__ pkd,
        float* __restrict__ outq, float* __restrict__ out_idx_f,
        float* __restrict__ loss_q, int* __restrict__ counts) {
    const int lane = threadIdx.x & 63, w = threadIdx.x >> 6;
    const int q = blockIdx.x * 4 + w;
    float4 x4 = *(const float4*)&X[(size_t)q * DIM + lane * 4];

    double wk = -INFINITY;
    if (lane < 32)
        wk = pkd[(((size_t)(lane >> 2) * NQ_TOTAL + q) * TOPS) + (lane & 3)];

    int kc[8];
#pragma unroll
    for (int t = 0; t < 8; ++t) {
        double m = wk;
#pragma unroll
        for (int o = 1; o < 64; o <<= 1) m = fmax(m, __shfl_xor(m, o));
        kc[t] = (int)(__builtin_bit_cast(unsigned long long, m) & 8191ull);
        if (wk == m) wk = -INFINITY;               // remove winner (keys unique)
    }

    float sb = -FLT_MAX; int kb = 0; float4 eb = x4;
#pragma unroll
    for (int t = 0; t < 8; ++t) {
        int k = kc[t];
        float4 e4 = *(const float4*)&ET[(size_t)k * DIM + lane * 4];
        float pr = x4.x * e4.x + x4.y * e4.y + x4.z * e4.z + x4.w * e4.w;
#pragma unroll
        for (int o = 1; o < 64; o <<= 1) pr += __shfl_xor(pr, o);
        float s = 2.f * pr - norms[k];
        bool better = (s > sb) || (s == sb && k < kb);
        if (better) { sb = s; kb = k; eb = e4; }
    }
    float4 d4 = {eb.x - x4.x, eb.y - x4.y, eb.z - x4.z, eb.w - x4.w};
    float4 o4 = {x4.x + d4.x, x4.y + d4.y, x4.z + d4.z, x4.w + d4.w};
    *(float4*)&outq[(size_t)q * DIM + lane * 4] = o4;
    float l = d4.x * d4.x + d4.y * d4.y + d4.z * d4.z + d4.w * d4.w;
#pragma unroll
    for (int o = 1; o < 64; o <<= 1) l += __shfl_xor(l, o);
    if (lane == 0) {
        out_idx_f[q] = (float)kb;
        loss_q[q] = l;
        atomicAdd(&counts[kb], 1);
    }
}

// ---------------------------------------------------------------- scalars
__global__ __launch_bounds__(256) void final_scalars(
        const int* __restrict__ counts, const float* __restrict__ loss_q,
        float* __restrict__ out_sc) {
    int t = threadIdx.x;
    float ls = 0.f;
    for (int i = t; i < NQ_TOTAL; i += 256) ls += loss_q[i];
    float ent = 0.f;
    for (int k = t; k < K_CODES; k += 256) {
        float p = (float)counts[k] / (float)NQ_TOTAL;
        ent -= p * logf(p + 1e-10f);
    }
#pragma unroll
    for (int o = 1; o < 64; o <<= 1) { ls += __shfl_xor(ls, o); ent += __shfl_xor(ent, o); }
    __shared__ float rl[4], re[4];
    if ((t & 63) == 0) { rl[t >> 6] = ls; re[t >> 6] = ent; }
    __syncthreads();
    if (t == 0) {
        float L = rl[0] + rl[1] + rl[2] + rl[3];
        float Ee = re[0] + re[1] + re[2] + re[3];
        float mse = L / (float)((size_t)NQ_TOTAL * DIM);
        out_sc[0] = 1.1f * mse;                         // e_latent + 0.1*q_latent
        out_sc[1] = -0.1f * (Ee / logf((float)K_CODES));
    }
}

extern "C" void kernel_launch(void* const* d_in, const int* in_sizes, int n_in,
                              void* d_out, int out_size, void* d_ws, size_t ws_size,
                              hipStream_t stream) {
    const float* X = (const float*)d_in[0];   // [32768, 256] fp32
    const float* E = (const float*)d_in[1];   // [256, 8192]  fp32

    float* out       = (float*)d_out;
    float* outq      = out;                           // 8388608
    float* out_idx_f = out + (size_t)NQ_TOTAL * DIM;  // 32768 (indices as f32)
    float* out_sc    = out_idx_f + NQ_TOTAL;          // 2 scalars

    char* ws = (char*)d_ws;
    int*            counts = (int*)(ws + WS_COUNTS);
    float*          loss_q = (float*)(ws + WS_LOSSQ);
    float*          norms  = (float*)(ws + WS_NORMS);
    double*         pkd    = (double*)(ws + WS_PKD);
    float*          ET     = (float*)(ws + WS_ET);
    unsigned short* Ahi    = (unsigned short*)(ws + WS_AHI);
    unsigned short* Bhi    = (unsigned short*)(ws + WS_BHI);

    hipMemsetAsync(counts, 0, K_CODES * sizeof(int), stream);
    prep_E<<<K_CODES / 32, 256, 0, stream>>>(E, Ahi, ET, norms);
    pack_XB<<<XBLOCKS + 256, 256, 0, stream>>>(X, Bhi);
    argmax_mfma<<<dim3(CSPLIT, NQ_TOTAL / 64), 256, 0, stream>>>(Ahi, Bhi, pkd);
    finalize_q<<<NQ_TOTAL / 4, 256, 0, stream>>>(X, ET, norms, pkd, outq, out_idx_f, loss_q, counts);
    final_scalars<<<1, 256, 0, stream>>>(counts, loss_q, out_sc);
}